// Round 2
// baseline (906.064 us; speedup 1.0000x reference)
//
#include <hip/hip_runtime.h>
#include <stdint.h>
#include <math.h>

#define DD 1024
#define SS 1000
#define BB 8
#define HH 16
#define MIDD 4096
#define OUTD 1000

typedef unsigned short u16;
typedef __attribute__((ext_vector_type(4))) float f32x4;
typedef __attribute__((ext_vector_type(4))) unsigned int u32x4;

__device__ __forceinline__ u16 f2b(float f) {
    union { float f; uint32_t u; } v; v.f = f;
    uint32_t r = v.u + 0x7fffu + ((v.u >> 16) & 1u);
    return (u16)(r >> 16);
}
__device__ __forceinline__ float b2f(u16 b) {
    union { uint32_t u; float f; } v; v.u = ((uint32_t)b) << 16; return v.f;
}

// ---- MFMA via inline asm ----
__device__ __forceinline__ void mfma_b16(f32x4& d, u32x4 a, u32x4 b) {
    asm("v_mfma_f32_16x16x32_bf16 %0, %1, %2, %0" : "+v"(d) : "v"(a), "v"(b));
}
#define MFMA_FENCE() do { __builtin_amdgcn_sched_barrier(0); \
    asm volatile("s_nop 7\n\ts_nop 7\n\ts_nop 7" ::); \
    __builtin_amdgcn_sched_barrier(0); } while (0)

#define GLDS16(gp, lp) \
    __builtin_amdgcn_global_load_lds((const __attribute__((address_space(1))) uint32_t*)(gp), \
                                     (__attribute__((address_space(3))) uint32_t*)(lp), 16, 0, 0)

// ---------------- posenc add + bf16 cast ----------------
__global__ void k_posenc(const float* __restrict__ x, u16* __restrict__ xpe) {
    long i = (long)blockIdx.x * 256 + threadIdx.x;
    if (i >= (long)BB * SS * DD) return;
    int d = (int)(i & (DD - 1));
    int s = (int)((i >> 10) % SS);
    float dv = __expf((float)(d & ~1) * (-9.210340371976184f / (float)DD));
    float ang = (float)s * dv;
    float pe = (d & 1) ? cosf(ang) : sinf(ang);
    xpe[i] = f2b(x[i] + pe);
}

// ---------------- weight transpose + bf16 cast: W[R][C] -> Wt[C][R] ----------------
__global__ void k_wt(const float* __restrict__ W, u16* __restrict__ Wt, int R, int C) {
    __shared__ float tile[32][33];
    int bc = blockIdx.x * 32, br = blockIdx.y * 32;
    int tx = threadIdx.x, ty = threadIdx.y;
#pragma unroll
    for (int i = 0; i < 32; i += 8)
        tile[ty + i][tx] = W[(long)(br + ty + i) * C + bc + tx];
    __syncthreads();
#pragma unroll
    for (int i = 0; i < 32; i += 8)
        Wt[(long)(bc + ty + i) * R + br + tx] = f2b(tile[tx][ty + i]);
}

// ---------------- generic bf16 GEMM: C = A * Bt^T  (Bt is [N][K]) ----------------
// MODE 0: fp32 store  MODE 1: bf16 store  MODE 2: bf16 relu(acc+bias)
// MODE 3: fp32 store of acc + bias[col] + bf16res[row*ldc+col]
template<int MODE>
__global__ __launch_bounds__(256)
void k_gemm(const u16* __restrict__ A, const u16* __restrict__ Bt, void* __restrict__ Cp,
            const float* __restrict__ bias, const u16* __restrict__ res,
            int M, int N, int K, int lda, int ldb, int ldc)
{
    __shared__ u16 As[128 * 32];
    __shared__ u16 Bs[128 * 32];
    const int t = threadIdx.x;
    const int lane = t & 63, wave = t >> 6;
    const int bm = blockIdx.y * 128, bn = blockIdx.x * 128;

    const int sr = t >> 2;
    const int sc = (t & 3) * 8;
    const u16* Ag0 = A + (long)(bm + sr) * lda + sc;
    const u16* Ag1 = A + (long)(bm + 64 + sr) * lda + sc;
    const u16* Bg0 = Bt + (long)(bn + sr) * ldb + sc;
    const u16* Bg1 = Bt + (long)(bn + 64 + sr) * ldb + sc;
    const bool a0 = (bm + sr) < M, a1 = (bm + 64 + sr) < M;
    const bool b0 = (bn + sr) < N, b1 = (bn + 64 + sr) < N;
    u16* AsW0 = As + wave * 512;
    u16* AsW1 = As + 2048 + wave * 512;
    u16* BsW0 = Bs + wave * 512;
    u16* BsW1 = Bs + 2048 + wave * 512;

    const int wr = (wave >> 1) * 64, wc = (wave & 1) * 64;
    const int lr = lane & 15, lk = (lane >> 4) * 8;

    f32x4 acc[4][4] = {};

    for (int k0 = 0; k0 < K; k0 += 32) {
        __syncthreads();
        if (a0) GLDS16(Ag0, AsW0);
        if (a1) GLDS16(Ag1, AsW1);
        if (b0) GLDS16(Bg0, BsW0);
        if (b1) GLDS16(Bg1, BsW1);
        Ag0 += 32; Ag1 += 32; Bg0 += 32; Bg1 += 32;
        __syncthreads();
        u32x4 af[4], bfr[4];
#pragma unroll
        for (int m = 0; m < 4; ++m)
            af[m] = *(const u32x4*)&As[(wr + m * 16 + lr) * 32 + lk];
#pragma unroll
        for (int n = 0; n < 4; ++n)
            bfr[n] = *(const u32x4*)&Bs[(wc + n * 16 + lr) * 32 + lk];
#pragma unroll
        for (int m = 0; m < 4; ++m)
#pragma unroll
            for (int n = 0; n < 4; ++n)
                mfma_b16(acc[m][n], af[m], bfr[n]);
    }

    MFMA_FENCE();

    const int g4 = (lane >> 4) * 4;
#pragma unroll
    for (int m = 0; m < 4; ++m) {
#pragma unroll
        for (int j = 0; j < 4; ++j) {
            const int r = bm + wr + m * 16 + g4 + j;
            if (r >= M) continue;
            const long ro = (long)r * ldc;
#pragma unroll
            for (int n = 0; n < 4; ++n) {
                const int c = bn + wc + n * 16 + lr;
                if (c >= N) continue;
                float v = acc[m][n][j];
                if (MODE == 0)      ((float*)Cp)[ro + c] = v;
                else if (MODE == 1) ((u16*)Cp)[ro + c] = f2b(v);
                else if (MODE == 2) { v += bias[c]; ((u16*)Cp)[ro + c] = f2b(v > 0.f ? v : 0.f); }
                else                { v += bias[c] + b2f(res[ro + c]); ((float*)Cp)[ro + c] = v; }
            }
        }
    }
}

// ---------------- V [8000][1024] bf16 -> Vt [B*H][64][1024] (s-major, zero-padded s>=1000) ----------------
__global__ void k_vt(const u16* __restrict__ V, u16* __restrict__ Vt) {
    __shared__ u16 tile[128][80];
    int b = blockIdx.z, h = blockIdx.y, s0 = blockIdx.x * 128;
    int t = threadIdx.x;
    int rr = t >> 3, cc = (t & 7) * 8;
#pragma unroll
    for (int p = 0; p < 4; ++p) {
        int s = s0 + p * 32 + rr;
        uint4 val = make_uint4(0u, 0u, 0u, 0u);
        if (s < SS) val = *(const uint4*)&V[((long)(b * SS + s)) * DD + h * 64 + cc];
        *(uint4*)&tile[p * 32 + rr][cc] = val;
    }
    __syncthreads();
    int d = t >> 2, sg = (t & 3) * 32;
    long base = ((long)((b * HH + h) * 64 + d)) * 1024 + s0 + sg;
#pragma unroll
    for (int i = 0; i < 4; ++i) {
        u16 tmp[8];
#pragma unroll
        for (int jj = 0; jj < 8; ++jj) tmp[jj] = tile[sg + i * 8 + jj][d];
        *(uint4*)&Vt[base + i * 8] = *(uint4*)tmp;
    }
}

// ---------------- fused flash attention ----------------
// grid (8 q-tiles, 16 h, 8 b), 256 threads. Q,K: [8000][1024] bf16. Vt: [B*H][64][1024].
__global__ __launch_bounds__(256)
void k_flash(const u16* __restrict__ Q, const u16* __restrict__ K,
             const u16* __restrict__ Vt, u16* __restrict__ ctx)
{
    __shared__ u16 Ps[128 * 64];   // Q staging, then P tiles (wave-private rows)
    __shared__ u16 Ks[64 * 64];
    __shared__ u16 Vs[64 * 64];    // Vs[d][k]
    const int t = threadIdx.x, lane = t & 63, wave = t >> 6;
    const int lr = lane & 15, g = lane >> 4;
    const int q0 = blockIdx.x * 128;
    const int h = blockIdx.y, b = blockIdx.z;
    const u16* Qg = Q + (long)b * 1024000 + h * 64;
    const u16* Kg = K + (long)b * 1024000 + h * 64;
    const u16* Vg = Vt + (long)(b * HH + h) * 65536;

    const int sr8 = wave * 8 + (lane >> 3);
    const int sc8 = (lane & 7) * 8;

    // stage Q tile [128][64]
#pragma unroll
    for (int r = 0; r < 4; ++r)
        if (q0 + r * 32 + sr8 < SS)
            GLDS16(Qg + (long)(q0 + r * 32 + sr8) * 1024 + sc8, &Ps[(r * 32 + wave * 8) * 64]);
    __syncthreads();
    u32x4 qa[2][2];
#pragma unroll
    for (int m = 0; m < 2; ++m)
#pragma unroll
        for (int ks = 0; ks < 2; ++ks)
            qa[m][ks] = *(const u32x4*)&Ps[(wave * 32 + m * 16 + lr) * 64 + ks * 32 + g * 8];

    f32x4 o[2][4] = {};
    float mrun[8], lrun[8];
#pragma unroll
    for (int i = 0; i < 8; ++i) { mrun[i] = -1e30f; lrun[i] = 0.f; }

    for (int kt = 0; kt < 1024; kt += 64) {
        __syncthreads();   // prev-iter LDS reads done (and Q frags read, iter 0)
#pragma unroll
        for (int r = 0; r < 2; ++r) {
            if (kt + r * 32 + sr8 < SS)
                GLDS16(Kg + (long)(kt + r * 32 + sr8) * 1024 + sc8, &Ks[(r * 32 + wave * 8) * 64]);
            GLDS16(Vg + (long)(r * 32 + sr8) * 1024 + kt + sc8, &Vs[(r * 32 + wave * 8) * 64]);
        }
        __syncthreads();

        f32x4 s[2][4] = {};
#pragma unroll
        for (int ks = 0; ks < 2; ++ks) {
            u32x4 kb[4];
#pragma unroll
            for (int n = 0; n < 4; ++n)
                kb[n] = *(const u32x4*)&Ks[(n * 16 + lr) * 64 + ks * 32 + g * 8];
#pragma unroll
            for (int m = 0; m < 2; ++m)
#pragma unroll
                for (int n = 0; n < 4; ++n)
                    mfma_b16(s[m][n], qa[m][ks], kb[n]);
        }
        MFMA_FENCE();

        // scale + mask padded k columns (NaN-proof: overwrite, never compute with garbage)
#pragma unroll
        for (int n = 0; n < 4; ++n) {
            const bool oob = (kt + n * 16 + lr) >= SS;
#pragma unroll
            for (int m = 0; m < 2; ++m)
#pragma unroll
                for (int j = 0; j < 4; ++j)
                    s[m][n][j] = oob ? -1e30f : s[m][n][j] * 0.125f;
        }

        // online softmax per row (row stats replicated across the 16-lane group)
#pragma unroll
        for (int m = 0; m < 2; ++m)
#pragma unroll
            for (int j = 0; j < 4; ++j) {
                const int ri = m * 4 + j;
                float mx = fmaxf(fmaxf(s[m][0][j], s[m][1][j]), fmaxf(s[m][2][j], s[m][3][j]));
                mx = fmaxf(mx, __shfl_xor(mx, 1));
                mx = fmaxf(mx, __shfl_xor(mx, 2));
                mx = fmaxf(mx, __shfl_xor(mx, 4));
                mx = fmaxf(mx, __shfl_xor(mx, 8));
                const float mn = fmaxf(mrun[ri], mx);
                const float al = __expf(mrun[ri] - mn);
                mrun[ri] = mn;
                float rs = 0.f;
#pragma unroll
                for (int n = 0; n < 4; ++n) {
                    float p = __expf(s[m][n][j] - mn);
                    s[m][n][j] = p; rs += p;
                }
                rs += __shfl_xor(rs, 1);
                rs += __shfl_xor(rs, 2);
                rs += __shfl_xor(rs, 4);
                rs += __shfl_xor(rs, 8);
                lrun[ri] = lrun[ri] * al + rs;
#pragma unroll
                for (int nd = 0; nd < 4; ++nd) o[m][nd][j] *= al;
#pragma unroll
                for (int n = 0; n < 4; ++n)
                    Ps[(wave * 32 + m * 16 + g * 4 + j) * 64 + n * 16 + lr] = f2b(s[m][n][j]);
            }

        // drain P writes before re-reading as A-fragments (wave-private rows, no barrier needed)
        asm volatile("s_waitcnt lgkmcnt(0)" ::: "memory");
        __builtin_amdgcn_sched_barrier(0);

        // PV: o += P * V
#pragma unroll
        for (int m = 0; m < 2; ++m) {
            u32x4 pa0 = *(const u32x4*)&Ps[(wave * 32 + m * 16 + lr) * 64 + g * 8];
            u32x4 pa1 = *(const u32x4*)&Ps[(wave * 32 + m * 16 + lr) * 64 + 32 + g * 8];
#pragma unroll
            for (int nd = 0; nd < 4; ++nd) {
                u32x4 vb0 = *(const u32x4*)&Vs[(nd * 16 + lr) * 64 + g * 8];
                u32x4 vb1 = *(const u32x4*)&Vs[(nd * 16 + lr) * 64 + 32 + g * 8];
                mfma_b16(o[m][nd], pa0, vb0);
                mfma_b16(o[m][nd], pa1, vb1);
            }
        }
    }

    MFMA_FENCE();

#pragma unroll
    for (int m = 0; m < 2; ++m)
#pragma unroll
        for (int j = 0; j < 4; ++j) {
            const int r = q0 + wave * 32 + m * 16 + g * 4 + j;
            if (r >= SS) continue;
            const float inv = 1.0f / lrun[m * 4 + j];
#pragma unroll
            for (int nd = 0; nd < 4; ++nd)
                ctx[((long)b * SS + r) * 1024 + h * 64 + nd * 16 + lr] = f2b(o[m][nd][j] * inv);
        }
}

// ---------------- LN stats (two stage, no atomics) ----------------
__global__ void k_stats1(const float* __restrict__ X, float* __restrict__ part) {
    int b = blockIdx.y, blk = blockIdx.x, t = threadIdx.x;
    const float* xp = X + (long)b * (SS * DD);
    float s = 0.f, q = 0.f;
    for (long i = (long)blk * 256 + t; i < (long)SS * DD; i += 128L * 256)
    { float x = xp[i]; s += x; q += x * x; }
#pragma unroll
    for (int o = 32; o; o >>= 1) { s += __shfl_xor(s, o, 64); q += __shfl_xor(q, o, 64); }
    __shared__ float rs[4], rq[4];
    if ((t & 63) == 0) { rs[t >> 6] = s; rq[t >> 6] = q; }
    __syncthreads();
    if (t == 0) {
        part[(b * 128 + blk) * 2]     = rs[0] + rs[1] + rs[2] + rs[3];
        part[(b * 128 + blk) * 2 + 1] = rq[0] + rq[1] + rq[2] + rq[3];
    }
}

__global__ void k_stats2(const float* __restrict__ part, float* __restrict__ st) {
    int b = blockIdx.x, t = threadIdx.x;
    float s = part[(b * 128 + t) * 2], q = part[(b * 128 + t) * 2 + 1];
#pragma unroll
    for (int o = 32; o; o >>= 1) { s += __shfl_xor(s, o, 64); q += __shfl_xor(q, o, 64); }
    __shared__ float rs[2], rq[2];
    if ((t & 63) == 0) { rs[t >> 6] = s; rq[t >> 6] = q; }
    __syncthreads();
    if (t == 0) {
        float sm = rs[0] + rs[1], sq = rq[0] + rq[1];
        float mean = sm / (float)(SS * DD);
        float var = sq / (float)(SS * DD) - mean * mean;
        st[b * 2] = mean;
        st[b * 2 + 1] = rsqrtf(var + 1e-5f);
    }
}

__global__ void k_lnapply(const float* __restrict__ X, const float* __restrict__ st,
                          u16* __restrict__ ob) {
    long i = (long)blockIdx.x * 256 + threadIdx.x;
    if (i >= (long)BB * SS * DD) return;
    int b = (int)(i / (long)(SS * DD));
    ob[i] = f2b((X[i] - st[b * 2]) * st[b * 2 + 1]);
}

// pooled[b][d] = rstd*(colmean - mean)   (LN + mean-pool fused)
__global__ void k_colpool(const float* __restrict__ F, const float* __restrict__ st,
                          float* __restrict__ pooled) {
    int b = blockIdx.y, d = blockIdx.x * 256 + threadIdx.x;
    const float* fp = F + (long)b * (SS * DD) + d;
    float s = 0.f;
    for (int ss = 0; ss < SS; ++ss) s += fp[(long)ss * DD];
    pooled[b * DD + d] = (s * (1.0f / SS) - st[b * 2]) * st[b * 2 + 1];
}

__global__ void k_out(const float* __restrict__ pooled, const float* __restrict__ Wout,
                      float* __restrict__ out) {
    int b = blockIdx.y, o = blockIdx.x * 256 + threadIdx.x;
    if (o >= OUTD) return;
    const float* pb = pooled + b * DD;
    float a = 0.f;
    for (int d = 0; d < DD; ++d) a += pb[d] * Wout[(long)d * OUTD + o];
    out[b * OUTD + o] = a;
}

extern "C" void kernel_launch(void* const* d_in, const int* in_sizes, int n_in,
                              void* d_out, int out_size, void* d_ws, size_t ws_size,
                              hipStream_t stream) {
    const float* x    = (const float*)d_in[0];
    const float* Wq   = (const float*)d_in[1];
    const float* Wk   = (const float*)d_in[2];
    const float* Wv   = (const float*)d_in[3];
    const float* Wo   = (const float*)d_in[4];
    const float* W1   = (const float*)d_in[5];
    const float* b1   = (const float*)d_in[6];
    const float* W2   = (const float*)d_in[7];
    const float* b2   = (const float*)d_in[8];
    const float* Wout = (const float*)d_in[9];
    float* out = (float*)d_out;

    // ---- arena (~107.5 MB), lifetime-overlapped ----
    char* base = (char*)d_ws;
    u16*   xpe    = (u16*)(base);                    // R0: xpe -> ctx (16,384,000)
    u16*   ctx    = xpe;
    u16*   Qb     = (u16*)(base + 16384000);         // R1: Qb+Kb -> ao
    u16*   Kb     = (u16*)(base + 32768000);
    float* ao     = (float*)(base + 16384000);       //     (fp32, 32,768,000 = Qb+Kb)
    u16*   Vb     = (u16*)(base + 49152000);         // R2: Vb -> attnb (16,384,000)
    u16*   attnb  = Vb;
    u16*   Vt     = (u16*)(base + 65536000);         // R3: Vt -> hb chunk (16,777,216)
    u16*   hb     = Vt;
    char*  wbase  = base + 82313216;                 // R4: weights (25,165,824)
    u16*   Wqt    = (u16*)(wbase);
    u16*   Wkt    = (u16*)(wbase + 2097152);
    u16*   Wvt    = (u16*)(wbase + 4194304);
    u16*   Wot    = (u16*)(wbase + 6291456);
    u16*   W1t    = (u16*)(wbase + 8388608);
    u16*   W2t    = (u16*)(wbase + 16777216);
    char*  mbase  = base + 107479040;                // R5: misc
    float* part   = (float*)(mbase);
    float* st1    = (float*)(mbase + 8192);
    float* st2    = (float*)(mbase + 8448);
    float* pooled = (float*)(mbase + 8704);

    dim3 blk(256);
    k_posenc<<<dim3(32000), blk, 0, stream>>>(x, xpe);
    k_wt<<<dim3(32, 32), dim3(32, 8), 0, stream>>>(Wq, Wqt, 1024, 1024);
    k_wt<<<dim3(32, 32), dim3(32, 8), 0, stream>>>(Wk, Wkt, 1024, 1024);
    k_wt<<<dim3(32, 32), dim3(32, 8), 0, stream>>>(Wv, Wvt, 1024, 1024);
    k_wt<<<dim3(32, 32), dim3(32, 8), 0, stream>>>(Wo, Wot, 1024, 1024);
    k_wt<<<dim3(128, 32), dim3(32, 8), 0, stream>>>(W1, W1t, 1024, 4096);
    k_wt<<<dim3(32, 128), dim3(32, 8), 0, stream>>>(W2, W2t, 4096, 1024);

    // QKV projections
    k_gemm<1><<<dim3(8, 63), blk, 0, stream>>>(xpe, Wqt, Qb, nullptr, nullptr, 8000, 1024, 1024, 1024, 1024, 1024);
    k_gemm<1><<<dim3(8, 63), blk, 0, stream>>>(xpe, Wkt, Kb, nullptr, nullptr, 8000, 1024, 1024, 1024, 1024, 1024);
    k_gemm<1><<<dim3(8, 63), blk, 0, stream>>>(xpe, Wvt, Vb, nullptr, nullptr, 8000, 1024, 1024, 1024, 1024, 1024);
    k_vt<<<dim3(8, 16, 8), blk, 0, stream>>>(Vb, Vt);

    // fused attention (writes ctx over xpe)
    k_flash<<<dim3(8, 16, 8), blk, 0, stream>>>(Qb, Kb, Vt, ctx);

    // output projection + LN (ao overwrites Qb/Kb)
    k_gemm<0><<<dim3(8, 63), blk, 0, stream>>>(ctx, Wot, ao, nullptr, nullptr, 8000, 1024, 1024, 1024, 1024, 1024);
    k_stats1<<<dim3(128, 8), blk, 0, stream>>>(ao, part);
    k_stats2<<<dim3(8), dim3(128), 0, stream>>>(part, st1);
    k_lnapply<<<dim3(32000), blk, 0, stream>>>(ao, st1, attnb);

    // FFN in 4 row-chunks (hb chunk lives in dead Vt slot); residual read from attnb (bf16)
    for (int c = 0; c < 4; ++c) {
        const long ro = (long)c * 2000 * 1024;
        k_gemm<2><<<dim3(32, 16), blk, 0, stream>>>(attnb + ro, W1t, hb, b1, nullptr,
                                                    2000, 4096, 1024, 1024, 1024, 4096);
        k_gemm<3><<<dim3(8, 16), blk, 0, stream>>>(hb, W2t, ao + ro, b2, attnb + ro,
                                                   2000, 1024, 4096, 4096, 4096, 1024);
    }

    k_stats1<<<dim3(128, 8), blk, 0, stream>>>(ao, part);
    k_stats2<<<dim3(8), dim3(128), 0, stream>>>(part, st2);
    k_colpool<<<dim3(4, 8), blk, 0, stream>>>(ao, st2, pooled);
    k_out<<<dim3(4, 8), blk, 0, stream>>>(pooled, Wout, out);
}

// Round 3
// 903.097 us; speedup vs baseline: 1.0033x; 1.0033x over previous
//
#include <hip/hip_runtime.h>
#include <stdint.h>
#include <math.h>

#define DD 1024
#define SS 1000
#define BB 8
#define HH 16
#define MIDD 4096
#define OUTD 1000

typedef unsigned short u16;
typedef __attribute__((ext_vector_type(4))) float f32x4;
typedef __attribute__((ext_vector_type(4))) unsigned int u32x4;

__device__ __forceinline__ u16 f2b(float f) {
    union { float f; uint32_t u; } v; v.f = f;
    uint32_t r = v.u + 0x7fffu + ((v.u >> 16) & 1u);
    return (u16)(r >> 16);
}
__device__ __forceinline__ float b2f(u16 b) {
    union { uint32_t u; float f; } v; v.u = ((uint32_t)b) << 16; return v.f;
}

// swizzled element offset for 64-elem (128B) rows: XOR 16B-chunk with row&7
__device__ __forceinline__ int sz64(int row, int e) {
    return row * 64 + ((((e >> 3) ^ row) & 7) << 3) + (e & 7);
}

// ---- MFMA via inline asm ----
__device__ __forceinline__ void mfma_b16(f32x4& d, u32x4 a, u32x4 b) {
    asm("v_mfma_f32_16x16x32_bf16 %0, %1, %2, %0" : "+v"(d) : "v"(a), "v"(b));
}
#define MFMA_FENCE() do { __builtin_amdgcn_sched_barrier(0); \
    asm volatile("s_nop 7\n\ts_nop 7\n\ts_nop 7" ::); \
    __builtin_amdgcn_sched_barrier(0); } while (0)

#define GLDS16(gp, lp) \
    __builtin_amdgcn_global_load_lds((const __attribute__((address_space(1))) uint32_t*)(gp), \
                                     (__attribute__((address_space(3))) uint32_t*)(lp), 16, 0, 0)

// ---------------- posenc add + bf16 cast (one sincos per pair) ----------------
__global__ void k_posenc(const float* __restrict__ x, u16* __restrict__ xpe) {
    long p = (long)blockIdx.x * 256 + threadIdx.x;      // pair index
    if (p >= (long)BB * SS * DD / 2) return;
    int dp = (int)(p & (DD / 2 - 1));                   // d/2
    int s = (int)((p >> 9) % SS);
    float dv = __expf((float)(2 * dp) * (-9.210340371976184f / (float)DD));
    float sn, cs;
    sincosf((float)s * dv, &sn, &cs);
    float2 xv = *(const float2*)&x[p * 2];
    uint32_t pk = (uint32_t)f2b(xv.x + sn) | ((uint32_t)f2b(xv.y + cs) << 16);
    ((uint32_t*)xpe)[p] = pk;
}

// ---------------- weight transpose + bf16 cast: W[R][C] -> Wt[C][R] ----------------
__global__ void k_wt(const float* __restrict__ W, u16* __restrict__ Wt, int R, int C) {
    __shared__ float tile[32][33];
    int bc = blockIdx.x * 32, br = blockIdx.y * 32;
    int tx = threadIdx.x, ty = threadIdx.y;
#pragma unroll
    for (int i = 0; i < 32; i += 8)
        tile[ty + i][tx] = W[(long)(br + ty + i) * C + bc + tx];
    __syncthreads();
#pragma unroll
    for (int i = 0; i < 32; i += 8)
        Wt[(long)(bc + ty + i) * R + br + tx] = f2b(tile[tx][ty + i]);
}

// ---------------- generic bf16 GEMM: C = A * Bt^T  (Bt is [N][K]) ----------------
// dbuf LDS + prefetch-before-compute (T3 minimum), 4-slot LDS swizzle, XCD swizzle.
// MODE 0: fp32 store  MODE 1: bf16 store  MODE 2: bf16 relu(acc+bias)
// MODE 3: fp32 store of acc + bias[col] + bf16res[row*ldc+col]
template<int MODE>
__global__ __launch_bounds__(256)
void k_gemm(const u16* __restrict__ A, const u16* __restrict__ Bt, void* __restrict__ Cp,
            const float* __restrict__ bias, const u16* __restrict__ res,
            int M, int N, int K, int lda, int ldb, int ldc)
{
    __shared__ u16 As[2][4096];
    __shared__ u16 Bs[2][4096];
    const int t = threadIdx.x;
    const int lane = t & 63, wave = t >> 6;

    // XCD-aware bijective swizzle (all launch grids have nwg % 8 == 0)
    const int nx = gridDim.x;
    int id = blockIdx.y * nx + blockIdx.x;
    const int nwg = nx * gridDim.y;
    if (!(nwg & 7)) id = (id & 7) * (nwg >> 3) + (id >> 3);
    const int bm = (id / nx) * 128, bn = (id % nx) * 128;

    const int sr = t >> 2;                       // staging row 0..63
    const int scs = (((t & 3) ^ (sr & 3)) * 8);  // swizzled source elem offset
    const u16* Ag0 = A + (long)(bm + sr) * lda + scs;
    const u16* Ag1 = A + (long)(bm + 64 + sr) * lda + scs;
    const u16* Bg0 = Bt + (long)(bn + sr) * ldb + scs;
    const u16* Bg1 = Bt + (long)(bn + 64 + sr) * ldb + scs;
    const bool a0 = (bm + sr) < M, a1 = (bm + 64 + sr) < M;
    const bool b0 = (bn + sr) < N, b1 = (bn + 64 + sr) < N;

    const int wr = (wave >> 1) * 64, wc = (wave & 1) * 64;
    const int lr = lane & 15, g = lane >> 4;

    f32x4 acc[4][4] = {};

#define STAGE(buf, k0) do { \
        if (a0) GLDS16(Ag0 + (k0), &As[buf][wave * 512]); \
        if (a1) GLDS16(Ag1 + (k0), &As[buf][2048 + wave * 512]); \
        if (b0) GLDS16(Bg0 + (k0), &Bs[buf][wave * 512]); \
        if (b1) GLDS16(Bg1 + (k0), &Bs[buf][2048 + wave * 512]); \
    } while (0)

    STAGE(0, 0);
    asm volatile("s_waitcnt vmcnt(0)" ::: "memory");
    __syncthreads();

    int cur = 0;
    for (int k0 = 0; k0 < K; k0 += 32) {
        if (k0 + 32 < K) STAGE(cur ^ 1, k0 + 32);   // issue next tile, no wait
        u32x4 af[4], bfr[4];
#pragma unroll
        for (int m = 0; m < 4; ++m) {
            const int ra = wr + m * 16 + lr;
            af[m] = *(const u32x4*)&As[cur][ra * 32 + (((g ^ ra) & 3) << 3)];
        }
#pragma unroll
        for (int n = 0; n < 4; ++n) {
            const int rb = wc + n * 16 + lr;
            bfr[n] = *(const u32x4*)&Bs[cur][rb * 32 + (((g ^ rb) & 3) << 3)];
        }
#pragma unroll
        for (int m = 0; m < 4; ++m)
#pragma unroll
            for (int n = 0; n < 4; ++n)
                mfma_b16(acc[m][n], af[m], bfr[n]);
        asm volatile("s_waitcnt vmcnt(0)" ::: "memory");
        __syncthreads();
        cur ^= 1;
    }
#undef STAGE

    MFMA_FENCE();

    const int g4 = g * 4;
#pragma unroll
    for (int m = 0; m < 4; ++m) {
#pragma unroll
        for (int j = 0; j < 4; ++j) {
            const int r = bm + wr + m * 16 + g4 + j;
            if (r >= M) continue;
            const long ro = (long)r * ldc;
#pragma unroll
            for (int n = 0; n < 4; ++n) {
                const int c = bn + wc + n * 16 + lr;
                if (c >= N) continue;
                float v = acc[m][n][j];
                if (MODE == 0)      ((float*)Cp)[ro + c] = v;
                else if (MODE == 1) ((u16*)Cp)[ro + c] = f2b(v);
                else if (MODE == 2) { v += bias[c]; ((u16*)Cp)[ro + c] = f2b(v > 0.f ? v : 0.f); }
                else                { v += bias[c] + b2f(res[ro + c]); ((float*)Cp)[ro + c] = v; }
            }
        }
    }
}

// ---------------- V part of QKV [8000][3072] -> Vt [B*H][64][1024] (s-major, zero-pad s>=1000) ----------------
__global__ void k_vt(const u16* __restrict__ QKV, u16* __restrict__ Vt) {
    __shared__ u16 tile[128][80];
    int b = blockIdx.z, h = blockIdx.y, s0 = blockIdx.x * 128;
    int t = threadIdx.x;
    int rr = t >> 3, cc = (t & 7) * 8;
#pragma unroll
    for (int p = 0; p < 4; ++p) {
        int s = s0 + p * 32 + rr;
        uint4 val = make_uint4(0u, 0u, 0u, 0u);
        if (s < SS) val = *(const uint4*)&QKV[((long)(b * SS + s)) * 3072 + 2048 + h * 64 + cc];
        *(uint4*)&tile[p * 32 + rr][cc] = val;
    }
    __syncthreads();
    int d = t >> 2, sg = (t & 3) * 32;
    long base = ((long)((b * HH + h) * 64 + d)) * 1024 + s0 + sg;
#pragma unroll
    for (int i = 0; i < 4; ++i) {
        u16 tmp[8];
#pragma unroll
        for (int jj = 0; jj < 8; ++jj) tmp[jj] = tile[sg + i * 8 + jj][d];
        *(uint4*)&Vt[base + i * 8] = *(uint4*)tmp;
    }
}

// ---------------- fused flash attention (LDS XOR-swizzled) ----------------
// grid (8 q-tiles, 16 h, 8 b), 256 threads. QKV: [8000][3072] bf16. Vt: [B*H][64][1024].
__global__ __launch_bounds__(256)
void k_flash(const u16* __restrict__ QKV, const u16* __restrict__ Vt, u16* __restrict__ ctx)
{
    __shared__ u16 Ps[128 * 64];   // Q staging, then P tiles (wave-private rows)
    __shared__ u16 Ks[64 * 64];
    __shared__ u16 Vs[64 * 64];    // Vs[d][k]
    const int t = threadIdx.x, lane = t & 63, wave = t >> 6;
    const int lr = lane & 15, g = lane >> 4;
    const int q0 = blockIdx.x * 128;
    const int h = blockIdx.y, b = blockIdx.z;
    const u16* Qg = QKV + (long)b * SS * 3072 + h * 64;
    const u16* Kg = Qg + 1024;
    const u16* Vg = Vt + (long)(b * HH + h) * 65536;

    const int sr8 = wave * 8 + (lane >> 3);
    const int ssrc = ((lane & 7) ^ (lane >> 3)) * 8;   // swizzled source elem offset

    // stage Q tile [128][64] (swizzled via pre-swizzled source)
#pragma unroll
    for (int r = 0; r < 4; ++r)
        if (q0 + r * 32 + sr8 < SS)
            GLDS16(Qg + (long)(q0 + r * 32 + sr8) * 3072 + ssrc, &Ps[(r * 32 + wave * 8) * 64]);
    __syncthreads();
    u32x4 qa[2][2];
#pragma unroll
    for (int m = 0; m < 2; ++m)
#pragma unroll
        for (int ks = 0; ks < 2; ++ks)
            qa[m][ks] = *(const u32x4*)&Ps[sz64(wave * 32 + m * 16 + lr, ks * 32 + g * 8)];

    f32x4 o[2][4] = {};
    float mrun[8], lrun[8];
#pragma unroll
    for (int i = 0; i < 8; ++i) { mrun[i] = -1e30f; lrun[i] = 0.f; }

    for (int kt = 0; kt < 1024; kt += 64) {
        __syncthreads();   // prev-iter LDS reads done (and Q frag reads, iter 0)
#pragma unroll
        for (int r = 0; r < 2; ++r) {
            if (kt + r * 32 + sr8 < SS)
                GLDS16(Kg + (long)(kt + r * 32 + sr8) * 3072 + ssrc, &Ks[(r * 32 + wave * 8) * 64]);
            GLDS16(Vg + (long)(r * 32 + sr8) * 1024 + kt + ssrc, &Vs[(r * 32 + wave * 8) * 64]);
        }
        __syncthreads();

        f32x4 s[2][4] = {};
#pragma unroll
        for (int ks = 0; ks < 2; ++ks) {
            u32x4 kb[4];
#pragma unroll
            for (int n = 0; n < 4; ++n)
                kb[n] = *(const u32x4*)&Ks[sz64(n * 16 + lr, ks * 32 + g * 8)];
#pragma unroll
            for (int m = 0; m < 2; ++m)
#pragma unroll
                for (int n = 0; n < 4; ++n)
                    mfma_b16(s[m][n], qa[m][ks], kb[n]);
        }
        MFMA_FENCE();

        // scale + mask padded k columns (overwrite, never compute with garbage)
#pragma unroll
        for (int n = 0; n < 4; ++n) {
            const bool oob = (kt + n * 16 + lr) >= SS;
#pragma unroll
            for (int m = 0; m < 2; ++m)
#pragma unroll
                for (int j = 0; j < 4; ++j)
                    s[m][n][j] = oob ? -1e30f : s[m][n][j] * 0.125f;
        }

        // online softmax per row (row stats replicated across the 16-lane group)
#pragma unroll
        for (int m = 0; m < 2; ++m)
#pragma unroll
            for (int j = 0; j < 4; ++j) {
                const int ri = m * 4 + j;
                float mx = fmaxf(fmaxf(s[m][0][j], s[m][1][j]), fmaxf(s[m][2][j], s[m][3][j]));
                mx = fmaxf(mx, __shfl_xor(mx, 1));
                mx = fmaxf(mx, __shfl_xor(mx, 2));
                mx = fmaxf(mx, __shfl_xor(mx, 4));
                mx = fmaxf(mx, __shfl_xor(mx, 8));
                const float mn = fmaxf(mrun[ri], mx);
                const float al = __expf(mrun[ri] - mn);
                mrun[ri] = mn;
                float rs = 0.f;
#pragma unroll
                for (int n = 0; n < 4; ++n) {
                    float p = __expf(s[m][n][j] - mn);
                    s[m][n][j] = p; rs += p;
                }
                rs += __shfl_xor(rs, 1);
                rs += __shfl_xor(rs, 2);
                rs += __shfl_xor(rs, 4);
                rs += __shfl_xor(rs, 8);
                lrun[ri] = lrun[ri] * al + rs;
#pragma unroll
                for (int nd = 0; nd < 4; ++nd) o[m][nd][j] *= al;
#pragma unroll
                for (int n = 0; n < 4; ++n)
                    Ps[sz64(wave * 32 + m * 16 + g * 4 + j, n * 16 + lr)] = f2b(s[m][n][j]);
            }

        // drain P writes before re-reading as A-fragments (wave-private rows)
        asm volatile("s_waitcnt lgkmcnt(0)" ::: "memory");
        __builtin_amdgcn_sched_barrier(0);

        // PV: o += P * V
#pragma unroll
        for (int m = 0; m < 2; ++m) {
            u32x4 pa0 = *(const u32x4*)&Ps[sz64(wave * 32 + m * 16 + lr, g * 8)];
            u32x4 pa1 = *(const u32x4*)&Ps[sz64(wave * 32 + m * 16 + lr, 32 + g * 8)];
#pragma unroll
            for (int nd = 0; nd < 4; ++nd) {
                u32x4 vb0 = *(const u32x4*)&Vs[sz64(nd * 16 + lr, g * 8)];
                u32x4 vb1 = *(const u32x4*)&Vs[sz64(nd * 16 + lr, 32 + g * 8)];
                mfma_b16(o[m][nd], pa0, vb0);
                mfma_b16(o[m][nd], pa1, vb1);
            }
        }
    }

    MFMA_FENCE();

#pragma unroll
    for (int m = 0; m < 2; ++m)
#pragma unroll
        for (int j = 0; j < 4; ++j) {
            const int r = q0 + wave * 32 + m * 16 + g * 4 + j;
            if (r >= SS) continue;
            const float inv = 1.0f / lrun[m * 4 + j];
#pragma unroll
            for (int nd = 0; nd < 4; ++nd)
                ctx[((long)b * SS + r) * 1024 + h * 64 + nd * 16 + lr] = f2b(o[m][nd][j] * inv);
        }
}

// ---------------- LN stats (two stage, no atomics) ----------------
__global__ void k_stats1(const float* __restrict__ X, float* __restrict__ part) {
    int b = blockIdx.y, blk = blockIdx.x, t = threadIdx.x;
    const float* xp = X + (long)b * (SS * DD);
    float s = 0.f, q = 0.f;
    for (long i = (long)blk * 256 + t; i < (long)SS * DD; i += 128L * 256)
    { float x = xp[i]; s += x; q += x * x; }
#pragma unroll
    for (int o = 32; o; o >>= 1) { s += __shfl_xor(s, o, 64); q += __shfl_xor(q, o, 64); }
    __shared__ float rs[4], rq[4];
    if ((t & 63) == 0) { rs[t >> 6] = s; rq[t >> 6] = q; }
    __syncthreads();
    if (t == 0) {
        part[(b * 128 + blk) * 2]     = rs[0] + rs[1] + rs[2] + rs[3];
        part[(b * 128 + blk) * 2 + 1] = rq[0] + rq[1] + rq[2] + rq[3];
    }
}

__global__ void k_stats2(const float* __restrict__ part, float* __restrict__ st) {
    int b = blockIdx.x, t = threadIdx.x;
    float s = part[(b * 128 + t) * 2], q = part[(b * 128 + t) * 2 + 1];
#pragma unroll
    for (int o = 32; o; o >>= 1) { s += __shfl_xor(s, o, 64); q += __shfl_xor(q, o, 64); }
    __shared__ float rs[2], rq[2];
    if ((t & 63) == 0) { rs[t >> 6] = s; rq[t >> 6] = q; }
    __syncthreads();
    if (t == 0) {
        float sm = rs[0] + rs[1], sq = rq[0] + rq[1];
        float mean = sm / (float)(SS * DD);
        float var = sq / (float)(SS * DD) - mean * mean;
        st[b * 2] = mean;
        st[b * 2 + 1] = rsqrtf(var + 1e-5f);
    }
}

__global__ void k_lnapply(const float* __restrict__ X, const float* __restrict__ st,
                          u16* __restrict__ ob) {
    long i = (long)blockIdx.x * 256 + threadIdx.x;
    if (i >= (long)BB * SS * DD) return;
    int b = (int)(i / (long)(SS * DD));
    ob[i] = f2b((X[i] - st[b * 2]) * st[b * 2 + 1]);
}

// pooled[b][d] = rstd*(colmean - mean)   (LN + mean-pool fused)
__global__ void k_colpool(const float* __restrict__ F, const float* __restrict__ st,
                          float* __restrict__ pooled) {
    int b = blockIdx.y, d = blockIdx.x * 256 + threadIdx.x;
    const float* fp = F + (long)b * (SS * DD) + d;
    float s = 0.f;
    for (int ss = 0; ss < SS; ++ss) s += fp[(long)ss * DD];
    pooled[b * DD + d] = (s * (1.0f / SS) - st[b * 2]) * st[b * 2 + 1];
}

__global__ void k_out(const float* __restrict__ pooled, const float* __restrict__ Wout,
                      float* __restrict__ out) {
    int b = blockIdx.y, o = blockIdx.x * 256 + threadIdx.x;
    if (o >= OUTD) return;
    const float* pb = pooled + b * DD;
    float a = 0.f;
    for (int d = 0; d < DD; ++d) a += pb[d] * Wout[(long)d * OUTD + o];
    out[b * OUTD + o] = a;
}

extern "C" void kernel_launch(void* const* d_in, const int* in_sizes, int n_in,
                              void* d_out, int out_size, void* d_ws, size_t ws_size,
                              hipStream_t stream) {
    const float* x    = (const float*)d_in[0];
    const float* Wq   = (const float*)d_in[1];
    const float* Wk   = (const float*)d_in[2];
    const float* Wv   = (const float*)d_in[3];
    const float* Wo   = (const float*)d_in[4];
    const float* W1   = (const float*)d_in[5];
    const float* b1   = (const float*)d_in[6];
    const float* W2   = (const float*)d_in[7];
    const float* b2   = (const float*)d_in[8];
    const float* Wout = (const float*)d_in[9];
    float* out = (float*)d_out;

    // ---- arena (~107.5 MB), lifetime-overlapped ----
    char* base = (char*)d_ws;
    u16*   xpe    = (u16*)(base);                    // R0: xpe -> ctx (16,384,000)
    u16*   ctx    = xpe;
    u16*   QKVb   = (u16*)(base + 16384000);         // R1: QKV [8000][3072] (49,152,000)
    float* ao     = (float*)(base + 16384000);       //     ao fp32 (32,768,000) over Q+K part
    u16*   attnb  = (u16*)(base + 49152000);         //     attnb over V part (16,384,000)
    u16*   Vt     = (u16*)(base + 65536000);         // R3: Vt -> hb chunk (16,777,216)
    u16*   hb     = Vt;
    char*  wbase  = base + 82313216;                 // R4: weights (25,165,824)
    u16*   Wqkvt  = (u16*)(wbase);                   //     [3072][1024]
    u16*   Wot    = (u16*)(wbase + 6291456);
    u16*   W1t    = (u16*)(wbase + 8388608);
    u16*   W2t    = (u16*)(wbase + 16777216);
    char*  mbase  = base + 107479040;                // R5: misc
    float* part   = (float*)(mbase);
    float* st1    = (float*)(mbase + 8192);
    float* st2    = (float*)(mbase + 8448);
    float* pooled = (float*)(mbase + 8704);

    dim3 blk(256);
    k_posenc<<<dim3(16000), blk, 0, stream>>>(x, xpe);
    k_wt<<<dim3(32, 32), dim3(32, 8), 0, stream>>>(Wq, Wqkvt, 1024, 1024);
    k_wt<<<dim3(32, 32), dim3(32, 8), 0, stream>>>(Wk, Wqkvt + 1048576, 1024, 1024);
    k_wt<<<dim3(32, 32), dim3(32, 8), 0, stream>>>(Wv, Wqkvt + 2097152, 1024, 1024);
    k_wt<<<dim3(32, 32), dim3(32, 8), 0, stream>>>(Wo, Wot, 1024, 1024);
    k_wt<<<dim3(128, 32), dim3(32, 8), 0, stream>>>(W1, W1t, 1024, 4096);
    k_wt<<<dim3(32, 128), dim3(32, 8), 0, stream>>>(W2, W2t, 4096, 1024);

    // fused QKV projection: [8000][3072]
    k_gemm<1><<<dim3(24, 63), blk, 0, stream>>>(xpe, Wqkvt, QKVb, nullptr, nullptr,
                                                8000, 3072, 1024, 1024, 1024, 3072);
    k_vt<<<dim3(8, 16, 8), blk, 0, stream>>>(QKVb, Vt);

    // fused attention (writes ctx over xpe)
    k_flash<<<dim3(8, 16, 8), blk, 0, stream>>>(QKVb, Vt, ctx);

    // output projection + LN (ao overwrites Q/K part of QKVb)
    k_gemm<0><<<dim3(8, 63), blk, 0, stream>>>(ctx, Wot, ao, nullptr, nullptr,
                                               8000, 1024, 1024, 1024, 1024, 1024);
    k_stats1<<<dim3(128, 8), blk, 0, stream>>>(ao, part);
    k_stats2<<<dim3(8), dim3(128), 0, stream>>>(part, st1);
    k_lnapply<<<dim3(32000), blk, 0, stream>>>(ao, st1, attnb);

    // FFN in 4 row-chunks (hb chunk lives in dead Vt slot); residual read from attnb (bf16)
    for (int c = 0; c < 4; ++c) {
        const long ro = (long)c * 2000 * 1024;
        k_gemm<2><<<dim3(32, 16), blk, 0, stream>>>(attnb + ro, W1t, hb, b1, nullptr,
                                                    2000, 4096, 1024, 1024, 1024, 4096);
        k_gemm<3><<<dim3(8, 16), blk, 0, stream>>>(hb, W2t, ao + ro, b2, attnb + ro,
                                                   2000, 1024, 4096, 4096, 4096, 1024);
    }

    k_stats1<<<dim3(128, 8), blk, 0, stream>>>(ao, part);
    k_stats2<<<dim3(8), dim3(128), 0, stream>>>(part, st2);
    k_colpool<<<dim3(4, 8), blk, 0, stream>>>(ao, st2, pooled);
    k_out<<<dim3(4, 8), blk, 0, stream>>>(pooled, Wout, out);
}

// Round 4
// 665.366 us; speedup vs baseline: 1.3618x; 1.3573x over previous
//
#include <hip/hip_runtime.h>
#include <stdint.h>
#include <math.h>

#define DD 1024
#define SS 1000
#define BB 8
#define HH 16
#define MIDD 4096
#define OUTD 1000

typedef unsigned short u16;
typedef __attribute__((ext_vector_type(4))) float f32x4;
typedef __attribute__((ext_vector_type(4))) unsigned int u32x4;

__device__ __forceinline__ u16 f2b(float f) {
    union { float f; uint32_t u; } v; v.f = f;
    uint32_t r = v.u + 0x7fffu + ((v.u >> 16) & 1u);
    return (u16)(r >> 16);
}
__device__ __forceinline__ float b2f(u16 b) {
    union { uint32_t u; float f; } v; v.u = ((uint32_t)b) << 16; return v.f;
}

// swizzled element offset for 64-elem (128B) rows: XOR 16B-chunk with row&7
__device__ __forceinline__ int sz64(int row, int e) {
    return row * 64 + ((((e >> 3) ^ row) & 7) << 3) + (e & 7);
}

__device__ __forceinline__ void mfma_b16(f32x4& d, u32x4 a, u32x4 b) {
    asm("v_mfma_f32_16x16x32_bf16 %0, %1, %2, %0" : "+v"(d) : "v"(a), "v"(b));
}
#define MFMA_FENCE() do { __builtin_amdgcn_sched_barrier(0); \
    asm volatile("s_nop 7\n\ts_nop 7\n\ts_nop 7" ::); \
    __builtin_amdgcn_sched_barrier(0); } while (0)

#define GLDS16(gp, lp) \
    __builtin_amdgcn_global_load_lds((const __attribute__((address_space(1))) uint32_t*)(gp), \
                                     (__attribute__((address_space(3))) uint32_t*)(lp), 16, 0, 0)

// ---------------- posenc add + bf16 cast ----------------
__global__ void k_posenc(const float* __restrict__ x, u16* __restrict__ xpe) {
    long p = (long)blockIdx.x * 256 + threadIdx.x;
    if (p >= (long)BB * SS * DD / 2) return;
    int dp = (int)(p & (DD / 2 - 1));
    int s = (int)((p >> 9) % SS);
    float dv = __expf((float)(2 * dp) * (-9.210340371976184f / (float)DD));
    float sn, cs;
    sincosf((float)s * dv, &sn, &cs);
    float2 xv = *(const float2*)&x[p * 2];
    uint32_t pk = (uint32_t)f2b(xv.x + sn) | ((uint32_t)f2b(xv.y + cs) << 16);
    ((uint32_t*)xpe)[p] = pk;
}

// ---------------- weight transpose + bf16 cast: W[R][C] -> Wt[C][R] ----------------
__global__ void k_wt(const float* __restrict__ W, u16* __restrict__ Wt, int R, int C) {
    __shared__ float tile[32][33];
    int bc = blockIdx.x * 32, br = blockIdx.y * 32;
    int tx = threadIdx.x, ty = threadIdx.y;
#pragma unroll
    for (int i = 0; i < 32; i += 8)
        tile[ty + i][tx] = W[(long)(br + ty + i) * C + bc + tx];
    __syncthreads();
#pragma unroll
    for (int i = 0; i < 32; i += 8)
        Wt[(long)(bc + ty + i) * R + br + tx] = f2b(tile[tx][ty + i]);
}

// ---------------- bf16 GEMM: C = A * Bt^T, tile 128x256x64, 3-buf LDS, vmcnt(6) ----------------
// MODE 0: fp32 store  MODE 1: bf16  MODE 2: bf16 relu(acc+bias)
// MODE 3: bf16 acc+bias+b2f(res)   MODE 4: bf16 rmw C += acc
template<int MODE>
__global__ __launch_bounds__(512)
void k_gemm(const u16* __restrict__ A, const u16* __restrict__ Bt, void* __restrict__ Cp,
            const float* __restrict__ bias, const u16* __restrict__ res,
            int M, int N, int K, int lda, int ldb, int ldc, int mtiles)
{
    __shared__ u16 SA[3][128 * 64];   // 48 KB
    __shared__ u16 SB[3][256 * 64];   // 96 KB
    const int t = threadIdx.x, lane = t & 63, wave = t >> 6;
    const int lr = lane & 15, g = lane >> 4;

    // bijective XCD swizzle (m204 form; works for any nwg)
    const int orig = blockIdx.x, nwg = gridDim.x;
    const int q8 = nwg >> 3, r8 = nwg & 7, xc = orig & 7;
    const int wg = (xc < r8 ? xc * (q8 + 1) : r8 * (q8 + 1) + (xc - r8) * q8) + (orig >> 3);
    const int bm = (wg % mtiles) * 128, bn = (wg / mtiles) * 256;

    // staging geometry: each wave owns 1KB chunks; lane -> (row srow, swizzled 16B slot)
    const int srow = lane >> 3;
    const int csrc = ((lane & 7) ^ srow) << 3;   // pre-swizzled source elem offset
    int ar0 = bm + wave * 16 + srow;      if (ar0 >= M) ar0 = M - 1;
    int ar1 = bm + wave * 16 + 8 + srow;  if (ar1 >= M) ar1 = M - 1;
    const u16* Ag0 = A + (long)ar0 * lda + csrc;
    const u16* Ag1 = A + (long)ar1 * lda + csrc;
    const u16* Bg0 = Bt + (long)(bn + wave * 32 + srow) * ldb + csrc;
    const u16* Bg1 = Bt + (long)(bn + wave * 32 + 8 + srow) * ldb + csrc;
    const u16* Bg2 = Bt + (long)(bn + wave * 32 + 16 + srow) * ldb + csrc;
    const u16* Bg3 = Bt + (long)(bn + wave * 32 + 24 + srow) * ldb + csrc;

#define STAGE(bufi, ko) do { \
        GLDS16(Ag0 + (ko), &SA[bufi][(wave * 2 + 0) * 512]); \
        GLDS16(Ag1 + (ko), &SA[bufi][(wave * 2 + 1) * 512]); \
        GLDS16(Bg0 + (ko), &SB[bufi][(wave * 4 + 0) * 512]); \
        GLDS16(Bg1 + (ko), &SB[bufi][(wave * 4 + 1) * 512]); \
        GLDS16(Bg2 + (ko), &SB[bufi][(wave * 4 + 2) * 512]); \
        GLDS16(Bg3 + (ko), &SB[bufi][(wave * 4 + 3) * 512]); \
    } while (0)

    const int nt = K >> 6;
    f32x4 acc[8][2] = {};

    STAGE(0, 0);
    if (nt > 1) STAGE(1, 64);

    int buf = 0, nb = 2;
    for (int tt = 0; tt < nt; ++tt) {
        // counted wait: tile tt landed, tile tt+1 (6 loads) stays in flight
        if (tt + 1 < nt) asm volatile("s_waitcnt vmcnt(6)" ::: "memory");
        else             asm volatile("s_waitcnt vmcnt(0)" ::: "memory");
        __builtin_amdgcn_s_barrier();
        __builtin_amdgcn_sched_barrier(0);
        if (tt + 2 < nt) { STAGE(nb, (tt + 2) * 64); }

#pragma unroll
        for (int ks = 0; ks < 2; ++ks) {
            const int e8 = (ks << 2) | g;
            const int sl = ((e8 ^ (lr & 7)) & 7) << 3;
            u32x4 av[8], bv[2];
#pragma unroll
            for (int m = 0; m < 8; ++m)
                av[m] = *(const u32x4*)&SA[buf][(m * 16 + lr) * 64 + sl];
#pragma unroll
            for (int n = 0; n < 2; ++n)
                bv[n] = *(const u32x4*)&SB[buf][(wave * 32 + n * 16 + lr) * 64 + sl];
            __builtin_amdgcn_s_setprio(1);
#pragma unroll
            for (int m = 0; m < 8; ++m)
#pragma unroll
                for (int n = 0; n < 2; ++n)
                    mfma_b16(acc[m][n], av[m], bv[n]);
            __builtin_amdgcn_s_setprio(0);
        }
        buf = (buf == 2) ? 0 : buf + 1;
        nb  = (nb == 2) ? 0 : nb + 1;
    }
#undef STAGE

    MFMA_FENCE();

#pragma unroll
    for (int m = 0; m < 8; ++m) {
#pragma unroll
        for (int j = 0; j < 4; ++j) {
            const int r = bm + m * 16 + g * 4 + j;
            if (r >= M) continue;
            const long ro = (long)r * ldc;
#pragma unroll
            for (int n = 0; n < 2; ++n) {
                const int c = bn + wave * 32 + n * 16 + lr;
                float v = acc[m][n][j];
                if (MODE == 0)      ((float*)Cp)[ro + c] = v;
                else if (MODE == 1) ((u16*)Cp)[ro + c] = f2b(v);
                else if (MODE == 2) { v += bias[c]; ((u16*)Cp)[ro + c] = f2b(v > 0.f ? v : 0.f); }
                else if (MODE == 3) { v += bias[c] + b2f(res[ro + c]); ((u16*)Cp)[ro + c] = f2b(v); }
                else                { u16* cp = &((u16*)Cp)[ro + c]; *cp = f2b(b2f(*cp) + v); }
            }
        }
    }
}

// ---------------- V part of QKV [8000][3072] -> Vt [B*H][64][1024] (zero-pad s>=1000) ----------------
__global__ void k_vt(const u16* __restrict__ QKV, u16* __restrict__ Vt) {
    __shared__ u16 tile[128][80];
    int b = blockIdx.z, h = blockIdx.y, s0 = blockIdx.x * 128;
    int t = threadIdx.x;
    int rr = t >> 3, cc = (t & 7) * 8;
#pragma unroll
    for (int p = 0; p < 4; ++p) {
        int s = s0 + p * 32 + rr;
        uint4 val = make_uint4(0u, 0u, 0u, 0u);
        if (s < SS) val = *(const uint4*)&QKV[((long)(b * SS + s)) * 3072 + 2048 + h * 64 + cc];
        *(uint4*)&tile[p * 32 + rr][cc] = val;
    }
    __syncthreads();
    int d = t >> 2, sg = (t & 3) * 32;
    long base = ((long)((b * HH + h) * 64 + d)) * 1024 + s0 + sg;
#pragma unroll
    for (int i = 0; i < 4; ++i) {
        u16 tmp[8];
#pragma unroll
        for (int jj = 0; jj < 8; ++jj) tmp[jj] = tile[sg + i * 8 + jj][d];
        *(uint4*)&Vt[base + i * 8] = *(uint4*)tmp;
    }
}

// ---------------- fused flash attention, dbuf K/V, XCD-local swizzle ----------------
// grid flat 1024. QKV: [8000][3072] bf16. Vt: [B*H][64][1024].
__global__ __launch_bounds__(256)
void k_flash(const u16* __restrict__ QKV, const u16* __restrict__ Vt, u16* __restrict__ ctx)
{
    __shared__ u16 Ps[128 * 64];
    __shared__ u16 Ks[2][64 * 64];
    __shared__ u16 Vs[2][64 * 64];
    const int t = threadIdx.x, lane = t & 63, wave = t >> 6;
    const int lr = lane & 15, g = lane >> 4;
    // decode: all 8 q-tiles of one (b,h) land on one XCD (dispatch d -> XCD d%8)
    const int f = blockIdx.x;
    const int bh = (f & 7) + ((f >> 6) << 3);
    const int q0 = ((f >> 3) & 7) * 128;
    const int h = bh & 15, b = bh >> 4;
    const u16* Qg = QKV + (long)b * SS * 3072 + h * 64;
    const u16* Kg = Qg + 1024;
    const u16* Vg = Vt + (long)bh * 65536;

    const int sr8 = wave * 8 + (lane >> 3);
    const int ssrc = ((lane & 7) ^ (lane >> 3)) * 8;

    // stage Q tile [128][64]
#pragma unroll
    for (int r = 0; r < 4; ++r) {
        int qr = q0 + r * 32 + sr8; if (qr >= SS) qr = SS - 1;
        GLDS16(Qg + (long)qr * 3072 + ssrc, &Ps[(r * 32 + wave * 8) * 64]);
    }
    __syncthreads();
    u32x4 qa[2][2];
#pragma unroll
    for (int m = 0; m < 2; ++m)
#pragma unroll
        for (int ks = 0; ks < 2; ++ks)
            qa[m][ks] = *(const u32x4*)&Ps[sz64(wave * 32 + m * 16 + lr, ks * 32 + g * 8)];

    f32x4 o[2][4] = {};
    float mrun[8], lrun[8];
#pragma unroll
    for (int i = 0; i < 8; ++i) { mrun[i] = -1e30f; lrun[i] = 0.f; }

#define STAGEKV(bufi, kt) do { \
        int kr0 = (kt) + sr8;      if (kr0 >= SS) kr0 = SS - 1; \
        int kr1 = (kt) + 32 + sr8; if (kr1 >= SS) kr1 = SS - 1; \
        GLDS16(Kg + (long)kr0 * 3072 + ssrc, &Ks[bufi][(wave * 8) * 64]); \
        GLDS16(Kg + (long)kr1 * 3072 + ssrc, &Ks[bufi][(32 + wave * 8) * 64]); \
        GLDS16(Vg + (long)sr8 * 1024 + (kt) + ssrc, &Vs[bufi][(wave * 8) * 64]); \
        GLDS16(Vg + (long)(32 + sr8) * 1024 + (kt) + ssrc, &Vs[bufi][(32 + wave * 8) * 64]); \
    } while (0)

    STAGEKV(0, 0);

    for (int tt = 0; tt < 16; ++tt) {
        const int kt = tt * 64;
        const int buf = tt & 1;
        __syncthreads();                       // drains tile tt loads; closes prev compute
        if (tt < 15) STAGEKV(buf ^ 1, kt + 64);

        f32x4 s[2][4] = {};
#pragma unroll
        for (int ks = 0; ks < 2; ++ks) {
            u32x4 kb[4];
#pragma unroll
            for (int n = 0; n < 4; ++n)
                kb[n] = *(const u32x4*)&Ks[buf][sz64(n * 16 + lr, ks * 32 + g * 8)];
            __builtin_amdgcn_s_setprio(1);
#pragma unroll
            for (int m = 0; m < 2; ++m)
#pragma unroll
                for (int n = 0; n < 4; ++n)
                    mfma_b16(s[m][n], qa[m][ks], kb[n]);
            __builtin_amdgcn_s_setprio(0);
        }
        MFMA_FENCE();

#pragma unroll
        for (int n = 0; n < 4; ++n) {
            const bool oob = (kt + n * 16 + lr) >= SS;
#pragma unroll
            for (int m = 0; m < 2; ++m)
#pragma unroll
                for (int j = 0; j < 4; ++j)
                    s[m][n][j] = oob ? -1e30f : s[m][n][j] * 0.125f;
        }

#pragma unroll
        for (int m = 0; m < 2; ++m)
#pragma unroll
            for (int j = 0; j < 4; ++j) {
                const int ri = m * 4 + j;
                float mx = fmaxf(fmaxf(s[m][0][j], s[m][1][j]), fmaxf(s[m][2][j], s[m][3][j]));
                mx = fmaxf(mx, __shfl_xor(mx, 1));
                mx = fmaxf(mx, __shfl_xor(mx, 2));
                mx = fmaxf(mx, __shfl_xor(mx, 4));
                mx = fmaxf(mx, __shfl_xor(mx, 8));
                const float mn = fmaxf(mrun[ri], mx);
                const float al = __expf(mrun[ri] - mn);
                mrun[ri] = mn;
                float rs = 0.f;
#pragma unroll
                for (int n = 0; n < 4; ++n) {
                    float p = __expf(s[m][n][j] - mn);
                    s[m][n][j] = p; rs += p;
                }
                rs += __shfl_xor(rs, 1);
                rs += __shfl_xor(rs, 2);
                rs += __shfl_xor(rs, 4);
                rs += __shfl_xor(rs, 8);
                lrun[ri] = lrun[ri] * al + rs;
#pragma unroll
                for (int nd = 0; nd < 4; ++nd) o[m][nd][j] *= al;
#pragma unroll
                for (int n = 0; n < 4; ++n)
                    Ps[sz64(wave * 32 + m * 16 + g * 4 + j, n * 16 + lr)] = f2b(s[m][n][j]);
            }

        asm volatile("s_waitcnt lgkmcnt(0)" ::: "memory");
        __builtin_amdgcn_sched_barrier(0);

#pragma unroll
        for (int m = 0; m < 2; ++m) {
            u32x4 pa0 = *(const u32x4*)&Ps[sz64(wave * 32 + m * 16 + lr, g * 8)];
            u32x4 pa1 = *(const u32x4*)&Ps[sz64(wave * 32 + m * 16 + lr, 32 + g * 8)];
            __builtin_amdgcn_s_setprio(1);
#pragma unroll
            for (int nd = 0; nd < 4; ++nd) {
                u32x4 vb0 = *(const u32x4*)&Vs[buf][sz64(nd * 16 + lr, g * 8)];
                u32x4 vb1 = *(const u32x4*)&Vs[buf][sz64(nd * 16 + lr, 32 + g * 8)];
                mfma_b16(o[m][nd], pa0, vb0);
                mfma_b16(o[m][nd], pa1, vb1);
            }
            __builtin_amdgcn_s_setprio(0);
        }
    }
#undef STAGEKV

    MFMA_FENCE();

#pragma unroll
    for (int m = 0; m < 2; ++m)
#pragma unroll
        for (int j = 0; j < 4; ++j) {
            const int r = q0 + wave * 32 + m * 16 + g * 4 + j;
            if (r >= SS) continue;
            const float inv = 1.0f / lrun[m * 4 + j];
#pragma unroll
            for (int nd = 0; nd < 4; ++nd)
                ctx[((long)b * SS + r) * 1024 + h * 64 + nd * 16 + lr] = f2b(o[m][nd][j] * inv);
        }
}

// ---------------- LN stats fp32 input ----------------
__global__ void k_stats1(const float* __restrict__ X, float* __restrict__ part) {
    int b = blockIdx.y, blk = blockIdx.x, t = threadIdx.x;
    const float* xp = X + (long)b * (SS * DD);
    float s = 0.f, q = 0.f;
    for (long i = (long)blk * 256 + t; i < (long)SS * DD; i += 128L * 256)
    { float x = xp[i]; s += x; q += x * x; }
#pragma unroll
    for (int o = 32; o; o >>= 1) { s += __shfl_xor(s, o, 64); q += __shfl_xor(q, o, 64); }
    __shared__ float rs[4], rq[4];
    if ((t & 63) == 0) { rs[t >> 6] = s; rq[t >> 6] = q; }
    __syncthreads();
    if (t == 0) {
        part[(b * 128 + blk) * 2]     = rs[0] + rs[1] + rs[2] + rs[3];
        part[(b * 128 + blk) * 2 + 1] = rq[0] + rq[1] + rq[2] + rq[3];
    }
}

// ---------------- LN stats bf16 input (vectorized) ----------------
__global__ void k_stats1b(const u16* __restrict__ X, float* __restrict__ part) {
    int b = blockIdx.y, blk = blockIdx.x, t = threadIdx.x;
    const uint4* xp = (const uint4*)(X + (long)b * (SS * DD));
    float s = 0.f, q = 0.f;
    for (int i = blk * 256 + t; i < SS * DD / 8; i += 128 * 256) {
        uint4 v = xp[i];
        uint32_t w[4] = { v.x, v.y, v.z, v.w };
#pragma unroll
        for (int jj = 0; jj < 4; ++jj) {
            float a = b2f((u16)(w[jj] & 0xffff)), c = b2f((u16)(w[jj] >> 16));
            s += a + c; q += a * a + c * c;
        }
    }
#pragma unroll
    for (int o = 32; o; o >>= 1) { s += __shfl_xor(s, o, 64); q += __shfl_xor(q, o, 64); }
    __shared__ float rs[4], rq[4];
    if ((t & 63) == 0) { rs[t >> 6] = s; rq[t >> 6] = q; }
    __syncthreads();
    if (t == 0) {
        part[(b * 128 + blk) * 2]     = rs[0] + rs[1] + rs[2] + rs[3];
        part[(b * 128 + blk) * 2 + 1] = rq[0] + rq[1] + rq[2] + rq[3];
    }
}

__global__ void k_stats2(const float* __restrict__ part, float* __restrict__ st) {
    int b = blockIdx.x, t = threadIdx.x;
    float s = part[(b * 128 + t) * 2], q = part[(b * 128 + t) * 2 + 1];
#pragma unroll
    for (int o = 32; o; o >>= 1) { s += __shfl_xor(s, o, 64); q += __shfl_xor(q, o, 64); }
    __shared__ float rs[2], rq[2];
    if ((t & 63) == 0) { rs[t >> 6] = s; rq[t >> 6] = q; }
    __syncthreads();
    if (t == 0) {
        float sm = rs[0] + rs[1], sq = rq[0] + rq[1];
        float mean = sm / (float)(SS * DD);
        float var = sq / (float)(SS * DD) - mean * mean;
        st[b * 2] = mean;
        st[b * 2 + 1] = rsqrtf(var + 1e-5f);
    }
}

__global__ void k_lnapply(const float* __restrict__ X, const float* __restrict__ st,
                          u16* __restrict__ ob) {
    long i = (long)blockIdx.x * 256 + threadIdx.x;
    if (i >= (long)BB * SS * DD) return;
    int b = (int)(i / (long)(SS * DD));
    ob[i] = f2b((X[i] - st[b * 2]) * st[b * 2 + 1]);
}

// pooled[b][d] = rstd*(colmean - mean), bf16 input
__global__ void k_colpoolb(const u16* __restrict__ F, const float* __restrict__ st,
                           float* __restrict__ pooled) {
    int b = blockIdx.y, d = blockIdx.x * 256 + threadIdx.x;
    const u16* fp = F + (long)b * (SS * DD) + d;
    float s = 0.f;
    for (int ss = 0; ss < SS; ++ss) s += b2f(fp[(long)ss * DD]);
    pooled[b * DD + d] = (s * (1.0f / SS) - st[b * 2]) * st[b * 2 + 1];
}

__global__ void k_out(const float* __restrict__ pooled, const float* __restrict__ Wout,
                      float* __restrict__ out) {
    int b = blockIdx.y, o = blockIdx.x * 256 + threadIdx.x;
    if (o >= OUTD) return;
    const float* pb = pooled + b * DD;
    float a = 0.f;
    for (int d = 0; d < DD; ++d) a += pb[d] * Wout[(long)d * OUTD + o];
    out[b * OUTD + o] = a;
}

extern "C" void kernel_launch(void* const* d_in, const int* in_sizes, int n_in,
                              void* d_out, int out_size, void* d_ws, size_t ws_size,
                              hipStream_t stream) {
    const float* x    = (const float*)d_in[0];
    const float* Wq   = (const float*)d_in[1];
    const float* Wk   = (const float*)d_in[2];
    const float* Wv   = (const float*)d_in[3];
    const float* Wo   = (const float*)d_in[4];
    const float* W1   = (const float*)d_in[5];
    const float* b1   = (const float*)d_in[6];
    const float* W2   = (const float*)d_in[7];
    const float* b2   = (const float*)d_in[8];
    const float* Wout = (const float*)d_in[9];
    float* out = (float*)d_out;

    // ---- arena (~107.5 MB, proven size), lifetime-overlapped ----
    char* base = (char*)d_ws;
    u16*   xpe    = (u16*)(base);                    // @0: xpe -> ctx -> fout (16.38MB)
    u16*   ctx    = xpe;
    u16*   fout   = xpe;
    u16*   QKVb   = (u16*)(base + 16384000);         // @16.4: QKV 49.2MB
    float* ao     = (float*)(base + 16384000);       //   then ao fp32 32.77MB
    u16*   hb     = (u16*)(base + 16384000);         //   then hb_half bf16 32.77MB
    u16*   attnb  = (u16*)(base + 49152000);         //   attnb 16.38MB (over V cols)
    u16*   Vt     = (u16*)(base + 65536000);         // @65.5: Vt 16.78MB
    char*  wbase  = base + 82313216;                 // @82.3: weights 25.2MB
    u16*   Wqkvt  = (u16*)(wbase);                   //   [3072][1024]
    u16*   Wot    = (u16*)(wbase + 6291456);
    u16*   W1t    = (u16*)(wbase + 8388608);         //   [4096][1024]
    u16*   W2t    = (u16*)(wbase + 16777216);        //   [1024][4096]
    char*  mbase  = base + 107479040;
    float* part   = (float*)(mbase);
    float* st1    = (float*)(mbase + 8192);
    float* st2    = (float*)(mbase + 8448);
    float* pooled = (float*)(mbase + 8704);

    dim3 blk(256);
    k_posenc<<<dim3(16000), blk, 0, stream>>>(x, xpe);
    k_wt<<<dim3(32, 32), dim3(32, 8), 0, stream>>>(Wq, Wqkvt, 1024, 1024);
    k_wt<<<dim3(32, 32), dim3(32, 8), 0, stream>>>(Wk, Wqkvt + 1048576, 1024, 1024);
    k_wt<<<dim3(32, 32), dim3(32, 8), 0, stream>>>(Wv, Wqkvt + 2097152, 1024, 1024);
    k_wt<<<dim3(32, 32), dim3(32, 8), 0, stream>>>(Wo, Wot, 1024, 1024);
    k_wt<<<dim3(128, 32), dim3(32, 8), 0, stream>>>(W1, W1t, 1024, 4096);
    k_wt<<<dim3(32, 128), dim3(32, 8), 0, stream>>>(W2, W2t, 4096, 1024);

    // fused QKV projection: [8000][3072]  (63 M-tiles x 12 N-tiles)
    k_gemm<1><<<dim3(63 * 12), dim3(512), 0, stream>>>(xpe, Wqkvt, QKVb, nullptr, nullptr,
                                                       8000, 3072, 1024, 1024, 1024, 3072, 63);
    k_vt<<<dim3(8, 16, 8), blk, 0, stream>>>(QKVb, Vt);

    // fused attention (writes ctx over xpe)
    k_flash<<<dim3(1024), blk, 0, stream>>>(QKVb, Vt, ctx);

    // output projection + LN over (S,D)
    k_gemm<0><<<dim3(63 * 4), dim3(512), 0, stream>>>(ctx, Wot, ao, nullptr, nullptr,
                                                      8000, 1024, 1024, 1024, 1024, 1024, 63);
    k_stats1<<<dim3(128, 8), blk, 0, stream>>>(ao, part);
    k_stats2<<<dim3(8), dim3(128), 0, stream>>>(part, st1);
    k_lnapply<<<dim3(32000), blk, 0, stream>>>(ao, st1, attnb);

    // FFN split over mid halves (hb_half 32MB over dead ao); fout bf16 accumulated
    for (int hh = 0; hh < 2; ++hh) {
        k_gemm<2><<<dim3(63 * 8), dim3(512), 0, stream>>>(attnb, W1t + (long)hh * 2048 * 1024, hb,
                                                          b1 + hh * 2048, nullptr,
                                                          8000, 2048, 1024, 1024, 1024, 2048, 63);
        if (hh == 0)
            k_gemm<3><<<dim3(63 * 4), dim3(512), 0, stream>>>(hb, W2t + 0, fout, b2, attnb,
                                                              8000, 1024, 2048, 2048, 4096, 1024, 63);
        else
            k_gemm<4><<<dim3(63 * 4), dim3(512), 0, stream>>>(hb, W2t + 2048, fout, b2, attnb,
                                                              8000, 1024, 2048, 2048, 4096, 1024, 63);
    }

    k_stats1b<<<dim3(128, 8), blk, 0, stream>>>(fout, part);
    k_stats2<<<dim3(8), dim3(128), 0, stream>>>(part, st2);
    k_colpoolb<<<dim3(4, 8), blk, 0, stream>>>(fout, st2, pooled);
    k_out<<<dim3(4, 8), blk, 0, stream>>>(pooled, Wout, out);
}

// Round 5
// 648.737 us; speedup vs baseline: 1.3967x; 1.0256x over previous
//
#include <hip/hip_runtime.h>
#include <stdint.h>
#include <math.h>

#define DD 1024
#define SS 1000
#define BB 8
#define HH 16
#define MIDD 4096
#define OUTD 1000

typedef unsigned short u16;
typedef __attribute__((ext_vector_type(4))) float f32x4;
typedef __attribute__((ext_vector_type(4))) unsigned int u32x4;

__device__ __forceinline__ u16 f2b(float f) {
    union { float f; uint32_t u; } v; v.f = f;
    uint32_t r = v.u + 0x7fffu + ((v.u >> 16) & 1u);
    return (u16)(r >> 16);
}
__device__ __forceinline__ float b2f(u16 b) {
    union { uint32_t u; float f; } v; v.u = ((uint32_t)b) << 16; return v.f;
}

// swizzled element offset for 64-elem (128B) rows: XOR 16B-chunk with row&7
__device__ __forceinline__ int sz64(int row, int e) {
    return row * 64 + ((((e >> 3) ^ row) & 7) << 3) + (e & 7);
}

__device__ __forceinline__ void mfma_b16(f32x4& d, u32x4 a, u32x4 b) {
    asm("v_mfma_f32_16x16x32_bf16 %0, %1, %2, %0" : "+v"(d) : "v"(a), "v"(b));
}
#define MFMA_FENCE() do { __builtin_amdgcn_sched_barrier(0); \
    asm volatile("s_nop 7\n\ts_nop 7\n\ts_nop 7" ::); \
    __builtin_amdgcn_sched_barrier(0); } while (0)

#define GLDS16(gp, lp) \
    __builtin_amdgcn_global_load_lds((const __attribute__((address_space(1))) uint32_t*)(gp), \
                                     (__attribute__((address_space(3))) uint32_t*)(lp), 16, 0, 0)

// ---------------- posenc add + bf16 cast ----------------
__global__ void k_posenc(const float* __restrict__ x, u16* __restrict__ xpe) {
    long p = (long)blockIdx.x * 256 + threadIdx.x;
    if (p >= (long)BB * SS * DD / 2) return;
    int dp = (int)(p & (DD / 2 - 1));
    int s = (int)((p >> 9) % SS);
    float dv = __expf((float)(2 * dp) * (-9.210340371976184f / (float)DD));
    float sn, cs;
    sincosf((float)s * dv, &sn, &cs);
    float2 xv = *(const float2*)&x[p * 2];
    uint32_t pk = (uint32_t)f2b(xv.x + sn) | ((uint32_t)f2b(xv.y + cs) << 16);
    ((uint32_t*)xpe)[p] = pk;
}

// ---------------- weight transpose + bf16 cast: W[R][C] -> Wt[C][R] ----------------
__global__ void k_wt(const float* __restrict__ W, u16* __restrict__ Wt, int R, int C) {
    __shared__ float tile[32][33];
    int bc = blockIdx.x * 32, br = blockIdx.y * 32;
    int tx = threadIdx.x, ty = threadIdx.y;
#pragma unroll
    for (int i = 0; i < 32; i += 8)
        tile[ty + i][tx] = W[(long)(br + ty + i) * C + bc + tx];
    __syncthreads();
#pragma unroll
    for (int i = 0; i < 32; i += 8)
        Wt[(long)(bc + ty + i) * R + br + tx] = f2b(tile[tx][ty + i]);
}

// ---------------- bf16 GEMM: C = A * Bt^T, tile 256x128x64, 8-phase, vmcnt(4) ----------------
// 8 waves: wm = wave>>2 (2 M-halves of 128 rows), wn = wave&3 (4 N-blocks of 32 cols)
// MODE 0: fp32 store  MODE 1: bf16  MODE 2: bf16 relu(acc+bias)
// MODE 3: bf16 acc+bias+b2f(res)   MODE 4: bf16 rmw C += acc
template<int MODE>
__global__ __launch_bounds__(512)
void k_gemm(const u16* __restrict__ A, const u16* __restrict__ Bt, void* __restrict__ Cp,
            const float* __restrict__ bias, const u16* __restrict__ res,
            int M, int N, int K, int lda, int ldb, int ldc, int mtiles)
{
    __shared__ u16 SA[2][256 * 64];   // 64 KB
    __shared__ u16 SB[2][128 * 64];   // 32 KB
    const int t = threadIdx.x, lane = t & 63, w = t >> 6;
    const int lr = lane & 15, g = lane >> 4;
    const int wm = w >> 2, wn = w & 3;

    // bijective XCD swizzle (m204 form)
    const int orig = blockIdx.x, nwg = gridDim.x;
    const int q8 = nwg >> 3, r8 = nwg & 7, xc = orig & 7;
    const int wg = (xc < r8 ? xc * (q8 + 1) : r8 * (q8 + 1) + (xc - r8) * q8) + (orig >> 3);
    const int bm = (wg % mtiles) * 256, bn = (wg / mtiles) * 128;

    // staging: part 0 = A rows 0-127, part 1 = A rows 128-255, part 2 = B rows 0-127.
    // each part: wave covers 16 rows (2 loads x 8 rows); lane -> row+lane>>3, swizzled chunk
    const int srow8 = lane >> 3;
    const int csrc = ((lane & 7) ^ srow8) << 3;   // pre-swizzled source elem offset
    const u16* ga[2][2];
    const u16* gb[2];
#pragma unroll
    for (int p = 0; p < 2; ++p)
#pragma unroll
        for (int l = 0; l < 2; ++l) {
            int r = bm + p * 128 + w * 16 + l * 8 + srow8;
            if (r >= M) r = M - 1;
            ga[p][l] = A + (long)r * lda + csrc;
        }
#pragma unroll
    for (int l = 0; l < 2; ++l)
        gb[l] = Bt + (long)(bn + w * 16 + l * 8 + srow8) * ldb + csrc;

#define STAGEPART(buf, k0, p) do { \
        if ((p) < 2) { \
            GLDS16(ga[p][0] + (k0), &SA[buf][((p) * 128 + w * 16) * 64]); \
            GLDS16(ga[p][1] + (k0), &SA[buf][((p) * 128 + w * 16 + 8) * 64]); \
        } else { \
            GLDS16(gb[0] + (k0), &SB[buf][(w * 16) * 64]); \
            GLDS16(gb[1] + (k0), &SB[buf][(w * 16 + 8) * 64]); \
        } \
    } while (0)

    f32x4 acc[8][2] = {};

#define PH(buf, kk) do { \
        u32x4 av[8], bv[2]; \
        _Pragma("unroll") \
        for (int m = 0; m < 8; ++m) \
            av[m] = *(const u32x4*)&SA[buf][sz64(wm * 128 + m * 16 + lr, (kk) * 32 + g * 8)]; \
        _Pragma("unroll") \
        for (int n = 0; n < 2; ++n) \
            bv[n] = *(const u32x4*)&SB[buf][sz64(wn * 32 + n * 16 + lr, (kk) * 32 + g * 8)]; \
        __builtin_amdgcn_s_setprio(1); \
        _Pragma("unroll") \
        for (int m = 0; m < 8; ++m) \
            _Pragma("unroll") \
            for (int n = 0; n < 2; ++n) \
                mfma_b16(acc[m][n], av[m], bv[n]); \
        __builtin_amdgcn_s_setprio(0); \
    } while (0)

    const int nt = K >> 6;   // K-tiles (even: K = 1024 or 2048)

    // prologue: tile 0 -> buf0 (6 loads in flight)
    STAGEPART(0, 0, 0); STAGEPART(0, 0, 1); STAGEPART(0, 0, 2);

    for (int tp = 0; tp < nt; tp += 2) {
        const int k1 = (tp + 1) << 6, k2 = (tp + 2) << 6;
        // ---- tile tp in buf0 ----
        // Ph1: stage next-tile parts 0,1 -> buf1; wait tile tp landed (4 newer in flight)
        STAGEPART(1, k1, 0); STAGEPART(1, k1, 1);
        asm volatile("s_waitcnt vmcnt(4)" ::: "memory");
        __builtin_amdgcn_s_barrier();
        PH(0, 0);
        __builtin_amdgcn_s_barrier();
        // Ph2: stage part 2 -> buf1
        STAGEPART(1, k1, 2);
        PH(0, 1);
        __builtin_amdgcn_s_barrier();
        // ---- tile tp+1 in buf1 ----
        // Ph3: stage tile tp+2 parts 0,1 -> buf0 (freed by Ph2 barrier); wait tile tp+1
        if (tp + 2 < nt) {
            STAGEPART(0, k2, 0); STAGEPART(0, k2, 1);
            asm volatile("s_waitcnt vmcnt(4)" ::: "memory");
        } else {
            asm volatile("s_waitcnt vmcnt(0)" ::: "memory");
        }
        __builtin_amdgcn_s_barrier();
        PH(1, 0);
        __builtin_amdgcn_s_barrier();
        // Ph4: stage part 2 -> buf0
        if (tp + 2 < nt) STAGEPART(0, k2, 2);
        PH(1, 1);
        __builtin_amdgcn_s_barrier();
    }
#undef PH
#undef STAGEPART

    MFMA_FENCE();

#pragma unroll
    for (int m = 0; m < 8; ++m) {
#pragma unroll
        for (int j = 0; j < 4; ++j) {
            const int r = bm + wm * 128 + m * 16 + g * 4 + j;
            if (r >= M) continue;
            const long ro = (long)r * ldc;
#pragma unroll
            for (int n = 0; n < 2; ++n) {
                const int c = bn + wn * 32 + n * 16 + lr;
                float v = acc[m][n][j];
                if (MODE == 0)      ((float*)Cp)[ro + c] = v;
                else if (MODE == 1) ((u16*)Cp)[ro + c] = f2b(v);
                else if (MODE == 2) { v += bias[c]; ((u16*)Cp)[ro + c] = f2b(v > 0.f ? v : 0.f); }
                else if (MODE == 3) { v += bias[c] + b2f(res[ro + c]); ((u16*)Cp)[ro + c] = f2b(v); }
                else                { u16* cp = &((u16*)Cp)[ro + c]; *cp = f2b(b2f(*cp) + v); }
            }
        }
    }
}

// ---------------- V part of QKV [8000][3072] -> Vt [B*H][64][1024] (zero-pad s>=1000) ----------------
__global__ void k_vt(const u16* __restrict__ QKV, u16* __restrict__ Vt) {
    __shared__ u16 tile[128][80];
    int b = blockIdx.z, h = blockIdx.y, s0 = blockIdx.x * 128;
    int t = threadIdx.x;
    int rr = t >> 3, cc = (t & 7) * 8;
#pragma unroll
    for (int p = 0; p < 4; ++p) {
        int s = s0 + p * 32 + rr;
        uint4 val = make_uint4(0u, 0u, 0u, 0u);
        if (s < SS) val = *(const uint4*)&QKV[((long)(b * SS + s)) * 3072 + 2048 + h * 64 + cc];
        *(uint4*)&tile[p * 32 + rr][cc] = val;
    }
    __syncthreads();
    int d = t >> 2, sg = (t & 3) * 32;
    long base = ((long)((b * HH + h) * 64 + d)) * 1024 + s0 + sg;
#pragma unroll
    for (int i = 0; i < 4; ++i) {
        u16 tmp[8];
#pragma unroll
        for (int jj = 0; jj < 8; ++jj) tmp[jj] = tile[sg + i * 8 + jj][d];
        *(uint4*)&Vt[base + i * 8] = *(uint4*)tmp;
    }
}

// ---------------- fused flash attention ----------------
// ones-column PV computes the softmax denominator; defer-max; last-tile-only masking.
__global__ __launch_bounds__(256)
void k_flash(const u16* __restrict__ QKV, const u16* __restrict__ Vt, u16* __restrict__ ctx)
{
    __shared__ u16 Ps[128 * 64];
    __shared__ u16 Ks[2][64 * 64];
    __shared__ u16 Vs[2][80 * 64];   // rows 64-79: static [1;0...] block for row-sum
    const int t = threadIdx.x, lane = t & 63, wave = t >> 6;
    const int lr = lane & 15, g = lane >> 4;
    const int f = blockIdx.x;
    const int bh = (f & 7) + ((f >> 6) << 3);     // all 8 q-tiles of one (b,h) on one XCD
    const int q0 = ((f >> 3) & 7) * 128;
    const int h = bh & 15, b = bh >> 4;
    const u16* Qg = QKV + (long)b * SS * 3072 + h * 64;
    const u16* Kg = Qg + 1024;
    const u16* Vg = Vt + (long)bh * 65536;

    const int sr8 = wave * 8 + (lane >> 3);
    const int ssrc = ((lane & 7) ^ (lane >> 3)) * 8;

    // stage Q tile [128][64]
#pragma unroll
    for (int r = 0; r < 4; ++r) {
        int qr = q0 + r * 32 + sr8; if (qr >= SS) qr = SS - 1;
        GLDS16(Qg + (long)qr * 3072 + ssrc, &Ps[(r * 32 + wave * 8) * 64]);
    }
    // static ones/zeros rows of Vs (both buffers)
    for (int i = t; i < 2 * 16 * 64; i += 256) {
        int bfi = i >> 10, rr2 = 64 + ((i >> 6) & 15), cc2 = i & 63;
        Vs[bfi][sz64(rr2, cc2)] = (rr2 == 64) ? (u16)0x3F80 : (u16)0;
    }
    __syncthreads();
    u32x4 qa[2][2];
#pragma unroll
    for (int m = 0; m < 2; ++m)
#pragma unroll
        for (int ks = 0; ks < 2; ++ks)
            qa[m][ks] = *(const u32x4*)&Ps[sz64(wave * 32 + m * 16 + lr, ks * 32 + g * 8)];

    f32x4 o[2][5] = {};
    float mrun[8];
#pragma unroll
    for (int i = 0; i < 8; ++i) mrun[i] = -1e30f;

#define STAGEKV(bufi, kt) do { \
        int kr0 = (kt) + sr8;      if (kr0 >= SS) kr0 = SS - 1; \
        int kr1 = (kt) + 32 + sr8; if (kr1 >= SS) kr1 = SS - 1; \
        GLDS16(Kg + (long)kr0 * 3072 + ssrc, &Ks[bufi][(wave * 8) * 64]); \
        GLDS16(Kg + (long)kr1 * 3072 + ssrc, &Ks[bufi][(32 + wave * 8) * 64]); \
        GLDS16(Vg + (long)sr8 * 1024 + (kt) + ssrc, &Vs[bufi][(wave * 8) * 64]); \
        GLDS16(Vg + (long)(32 + sr8) * 1024 + (kt) + ssrc, &Vs[bufi][(32 + wave * 8) * 64]); \
    } while (0)

    STAGEKV(0, 0);

    for (int tt = 0; tt < 16; ++tt) {
        const int kt = tt * 64;
        const int buf = tt & 1;
        __syncthreads();
        if (tt < 15) STAGEKV(buf ^ 1, kt + 64);

        f32x4 s[2][4] = {};
#pragma unroll
        for (int ks = 0; ks < 2; ++ks) {
            u32x4 kb[4];
#pragma unroll
            for (int n = 0; n < 4; ++n)
                kb[n] = *(const u32x4*)&Ks[buf][sz64(n * 16 + lr, ks * 32 + g * 8)];
            __builtin_amdgcn_s_setprio(1);
#pragma unroll
            for (int m = 0; m < 2; ++m)
#pragma unroll
                for (int n = 0; n < 4; ++n)
                    mfma_b16(s[m][n], qa[m][ks], kb[n]);
            __builtin_amdgcn_s_setprio(0);
        }
        MFMA_FENCE();

        if (tt == 15) {   // only the last tile has padded cols
#pragma unroll
            for (int n = 0; n < 4; ++n) {
                const bool oob = (kt + n * 16 + lr) >= SS;
                if (oob)
#pragma unroll
                    for (int m = 0; m < 2; ++m)
#pragma unroll
                        for (int j = 0; j < 4; ++j) s[m][n][j] = -1e30f;
            }
        }

        // online softmax: raw-unit max; scale folded into exp; denom via ones-column MFMA
#pragma unroll
        for (int m = 0; m < 2; ++m)
#pragma unroll
            for (int j = 0; j < 4; ++j) {
                const int ri = m * 4 + j;
                float mx = fmaxf(fmaxf(s[m][0][j], s[m][1][j]), fmaxf(s[m][2][j], s[m][3][j]));
                mx = fmaxf(mx, __shfl_xor(mx, 1));
                mx = fmaxf(mx, __shfl_xor(mx, 2));
                mx = fmaxf(mx, __shfl_xor(mx, 4));
                mx = fmaxf(mx, __shfl_xor(mx, 8));
                if (!__all(mx <= mrun[ri] + 64.f)) {   // defer-max: THR=8 in scaled units
                    const float mn = fmaxf(mrun[ri], mx);
                    const float al = __expf((mrun[ri] - mn) * 0.125f);
                    mrun[ri] = mn;
#pragma unroll
                    for (int nd = 0; nd < 5; ++nd) o[m][nd][j] *= al;
                }
                const float moff = mrun[ri] * 0.125f;
#pragma unroll
                for (int n = 0; n < 4; ++n) {
                    float p = __expf(fmaf(s[m][n][j], 0.125f, -moff));
                    Ps[sz64(wave * 32 + m * 16 + g * 4 + j, n * 16 + lr)] = f2b(p);
                }
            }

        asm volatile("s_waitcnt lgkmcnt(0)" ::: "memory");
        __builtin_amdgcn_sched_barrier(0);

        // PV: o += P * V   (nd=4 reads the static ones block -> denominator)
#pragma unroll
        for (int m = 0; m < 2; ++m) {
            u32x4 pa0 = *(const u32x4*)&Ps[sz64(wave * 32 + m * 16 + lr, g * 8)];
            u32x4 pa1 = *(const u32x4*)&Ps[sz64(wave * 32 + m * 16 + lr, 32 + g * 8)];
            __builtin_amdgcn_s_setprio(1);
#pragma unroll
            for (int nd = 0; nd < 5; ++nd) {
                u32x4 vb0 = *(const u32x4*)&Vs[buf][sz64(nd * 16 + lr, g * 8)];
                u32x4 vb1 = *(const u32x4*)&Vs[buf][sz64(nd * 16 + lr, 32 + g * 8)];
                mfma_b16(o[m][nd], pa0, vb0);
                mfma_b16(o[m][nd], pa1, vb1);
            }
            __builtin_amdgcn_s_setprio(0);
        }
    }
#undef STAGEKV

    MFMA_FENCE();

#pragma unroll
    for (int m = 0; m < 2; ++m)
#pragma unroll
        for (int j = 0; j < 4; ++j) {
            const int r = q0 + wave * 32 + m * 16 + g * 4 + j;
            if (r >= SS) continue;
            const float lval = __shfl(o[m][4][j], lane & 48);   // col 64 = sum(P) at lr=0
            const float inv = 1.0f / lval;
#pragma unroll
            for (int nd = 0; nd < 4; ++nd)
                ctx[((long)b * SS + r) * 1024 + h * 64 + nd * 16 + lr] = f2b(o[m][nd][j] * inv);
        }
}

// ---------------- LN stats fp32 input ----------------
__global__ void k_stats1(const float* __restrict__ X, float* __restrict__ part) {
    int b = blockIdx.y, blk = blockIdx.x, t = threadIdx.x;
    const float* xp = X + (long)b * (SS * DD);
    float s = 0.f, q = 0.f;
    for (long i = (long)blk * 256 + t; i < (long)SS * DD; i += 128L * 256)
    { float x = xp[i]; s += x; q += x * x; }
#pragma unroll
    for (int o = 32; o; o >>= 1) { s += __shfl_xor(s, o, 64); q += __shfl_xor(q, o, 64); }
    __shared__ float rs[4], rq[4];
    if ((t & 63) == 0) { rs[t >> 6] = s; rq[t >> 6] = q; }
    __syncthreads();
    if (t == 0) {
        part[(b * 128 + blk) * 2]     = rs[0] + rs[1] + rs[2] + rs[3];
        part[(b * 128 + blk) * 2 + 1] = rq[0] + rq[1] + rq[2] + rq[3];
    }
}

// ---------------- LN stats bf16 input (vectorized) ----------------
__global__ void k_stats1b(const u16* __restrict__ X, float* __restrict__ part) {
    int b = blockIdx.y, blk = blockIdx.x, t = threadIdx.x;
    const uint4* xp = (const uint4*)(X + (long)b * (SS * DD));
    float s = 0.f, q = 0.f;
    for (int i = blk * 256 + t; i < SS * DD / 8; i += 128 * 256) {
        uint4 v = xp[i];
        uint32_t w[4] = { v.x, v.y, v.z, v.w };
#pragma unroll
        for (int jj = 0; jj < 4; ++jj) {
            float a = b2f((u16)(w[jj] & 0xffff)), c = b2f((u16)(w[jj] >> 16));
            s += a + c; q += a * a + c * c;
        }
    }
#pragma unroll
    for (int o = 32; o; o >>= 1) { s += __shfl_xor(s, o, 64); q += __shfl_xor(q, o, 64); }
    __shared__ float rs[4], rq[4];
    if ((t & 63) == 0) { rs[t >> 6] = s; rq[t >> 6] = q; }
    __syncthreads();
    if (t == 0) {
        part[(b * 128 + blk) * 2]     = rs[0] + rs[1] + rs[2] + rs[3];
        part[(b * 128 + blk) * 2 + 1] = rq[0] + rq[1] + rq[2] + rq[3];
    }
}

__global__ void k_stats2(const float* __restrict__ part, float* __restrict__ st) {
    int b = blockIdx.x, t = threadIdx.x;
    float s = part[(b * 128 + t) * 2], q = part[(b * 128 + t) * 2 + 1];
#pragma unroll
    for (int o = 32; o; o >>= 1) { s += __shfl_xor(s, o, 64); q += __shfl_xor(q, o, 64); }
    __shared__ float rs[2], rq[2];
    if ((t & 63) == 0) { rs[t >> 6] = s; rq[t >> 6] = q; }
    __syncthreads();
    if (t == 0) {
        float sm = rs[0] + rs[1], sq = rq[0] + rq[1];
        float mean = sm / (float)(SS * DD);
        float var = sq / (float)(SS * DD) - mean * mean;
        st[b * 2] = mean;
        st[b * 2 + 1] = rsqrtf(var + 1e-5f);
    }
}

__global__ void k_lnapply(const float* __restrict__ X, const float* __restrict__ st,
                          u16* __restrict__ ob) {
    long i = (long)blockIdx.x * 256 + threadIdx.x;
    if (i >= (long)BB * SS * DD) return;
    int b = (int)(i / (long)(SS * DD));
    ob[i] = f2b((X[i] - st[b * 2]) * st[b * 2 + 1]);
}

// pooled[b][d] = rstd*(colmean - mean), bf16 input
__global__ void k_colpoolb(const u16* __restrict__ F, const float* __restrict__ st,
                           float* __restrict__ pooled) {
    int b = blockIdx.y, d = blockIdx.x * 256 + threadIdx.x;
    const u16* fp = F + (long)b * (SS * DD) + d;
    float s = 0.f;
    for (int ss = 0; ss < SS; ++ss) s += b2f(fp[(long)ss * DD]);
    pooled[b * DD + d] = (s * (1.0f / SS) - st[b * 2]) * st[b * 2 + 1];
}

__global__ void k_out(const float* __restrict__ pooled, const float* __restrict__ Wout,
                      float* __restrict__ out) {
    int b = blockIdx.y, o = blockIdx.x * 256 + threadIdx.x;
    if (o >= OUTD) return;
    const float* pb = pooled + b * DD;
    float a = 0.f;
    for (int d = 0; d < DD; ++d) a += pb[d] * Wout[(long)d * OUTD + o];
    out[b * OUTD + o] = a;
}

extern "C" void kernel_launch(void* const* d_in, const int* in_sizes, int n_in,
                              void* d_out, int out_size, void* d_ws, size_t ws_size,
                              hipStream_t stream) {
    const float* x    = (const float*)d_in[0];
    const float* Wq   = (const float*)d_in[1];
    const float* Wk   = (const float*)d_in[2];
    const float* Wv   = (const float*)d_in[3];
    const float* Wo   = (const float*)d_in[4];
    const float* W1   = (const float*)d_in[5];
    const float* b1   = (const float*)d_in[6];
    const float* W2   = (const float*)d_in[7];
    const float* b2   = (const float*)d_in[8];
    const float* Wout = (const float*)d_in[9];
    float* out = (float*)d_out;

    // ---- arena (~107.5 MB, proven size), lifetime-overlapped ----
    char* base = (char*)d_ws;
    u16*   xpe    = (u16*)(base);                    // @0: xpe -> ctx -> fout (16.38MB)
    u16*   ctx    = xpe;
    u16*   fout   = xpe;
    u16*   QKVb   = (u16*)(base + 16384000);         // @16.4: QKV 49.2MB
    float* ao     = (float*)(base + 16384000);       //   then ao fp32 32.77MB
    u16*   hb     = (u16*)(base + 16384000);         //   then hb_half bf16 32.77MB
    u16*   attnb  = (u16*)(base + 49152000);         //   attnb 16.38MB (over V cols)
    u16*   Vt     = (u16*)(base + 65536000);         // @65.5: Vt 16.78MB
    char*  wbase  = base + 82313216;                 // @82.3: weights 25.2MB
    u16*   Wqkvt  = (u16*)(wbase);                   //   [3072][1024]
    u16*   Wot    = (u16*)(wbase + 6291456);
    u16*   W1t    = (u16*)(wbase + 8388608);         //   [4096][1024]
    u16*   W2t    = (u16*)(wbase + 16777216);        //   [1024][4096]
    char*  mbase  = base + 107479040;
    float* part   = (float*)(mbase);
    float* st1    = (float*)(mbase + 8192);
    float* st2    = (float*)(mbase + 8448);
    float* pooled = (float*)(mbase + 8704);

    dim3 blk(256);
    k_posenc<<<dim3(16000), blk, 0, stream>>>(x, xpe);
    k_wt<<<dim3(32, 32), dim3(32, 8), 0, stream>>>(Wq, Wqkvt, 1024, 1024);
    k_wt<<<dim3(32, 32), dim3(32, 8), 0, stream>>>(Wk, Wqkvt + 1048576, 1024, 1024);
    k_wt<<<dim3(32, 32), dim3(32, 8), 0, stream>>>(Wv, Wqkvt + 2097152, 1024, 1024);
    k_wt<<<dim3(32, 32), dim3(32, 8), 0, stream>>>(Wo, Wot, 1024, 1024);
    k_wt<<<dim3(128, 32), dim3(32, 8), 0, stream>>>(W1, W1t, 1024, 4096);
    k_wt<<<dim3(32, 128), dim3(32, 8), 0, stream>>>(W2, W2t, 4096, 1024);

    // fused QKV projection: [8000][3072]  (32 m-tiles x 24 n-tiles = 768 wgs)
    k_gemm<1><<<dim3(768), dim3(512), 0, stream>>>(xpe, Wqkvt, QKVb, nullptr, nullptr,
                                                   8000, 3072, 1024, 1024, 1024, 3072, 32);
    k_vt<<<dim3(8, 16, 8), blk, 0, stream>>>(QKVb, Vt);

    // fused attention (writes ctx over xpe)
    k_flash<<<dim3(1024), blk, 0, stream>>>(QKVb, Vt, ctx);

    // output projection + LN over (S,D)   (32 x 8 = 256 wgs)
    k_gemm<0><<<dim3(256), dim3(512), 0, stream>>>(ctx, Wot, ao, nullptr, nullptr,
                                                   8000, 1024, 1024, 1024, 1024, 1024, 32);
    k_stats1<<<dim3(128, 8), blk, 0, stream>>>(ao, part);
    k_stats2<<<dim3(8), dim3(128), 0, stream>>>(part, st1);
    k_lnapply<<<dim3(32000), blk, 0, stream>>>(ao, st1, attnb);

    // FFN split over mid halves (hb_half over dead ao); fout bf16 accumulated
    for (int hh = 0; hh < 2; ++hh) {
        k_gemm<2><<<dim3(512), dim3(512), 0, stream>>>(attnb, W1t + (long)hh * 2048 * 1024, hb,
                                                       b1 + hh * 2048, nullptr,
                                                       8000, 2048, 1024, 1024, 1024, 2048, 32);
        if (hh == 0)
            k_gemm<3><<<dim3(256), dim3(512), 0, stream>>>(hb, W2t + 0, fout, b2, attnb,
                                                           8000, 1024, 2048, 2048, 4096, 1024, 32);
        else
            k_gemm<4><<<dim3(256), dim3(512), 0, stream>>>(hb, W2t + 2048, fout, b2, attnb,
                                                           8000, 1024, 2048, 2048, 4096, 1024, 32);
    }

    k_stats1b<<<dim3(128, 8), blk, 0, stream>>>(fout, part);
    k_stats2<<<dim3(8), dim3(128), 0, stream>>>(part, st2);
    k_colpoolb<<<dim3(4, 8), blk, 0, stream>>>(fout, st2, pooled);
    k_out<<<dim3(4, 8), blk, 0, stream>>>(pooled, Wout, out);
}